// Round 11
// baseline (270.970 us; speedup 1.0000x reference)
//
#include <hip/hip_runtime.h>
#include <hip/hip_cooperative_groups.h>
namespace cg = cooperative_groups;

#define KINST 64

struct SmStats { float ls[4][4][KINST]; int pal[KINST]; };
struct SmRed   { float red[256]; float scale[KINST]; int nu; };
struct SmPix   { float4 A[KINST + 1]; float4 Z[KINST + 1]; float W[KINST + 1];
                 float cwN[KINST][KINST + 1]; int pal[KINST];
                 float rA[4], rB[4]; int nonuni; };
struct SmFin   { float4 zf[KINST]; float r[5][4]; };
union SmAll { SmStats st; SmRed rd; SmPix px; SmFin fn; };

__device__ __forceinline__ int decode_k0(float t0, float t1, float t2,
                                         const int* pal_s) {
  int pid = (int)(fmaf(t0, 65536.f, fmaf(t1, 256.f, t2)) + 0.5f);
  if (pid >= 0 && pid < KINST && pal_s[pid] == pid) return pid;  // fast path
  for (int j = 0; j < KINST; ++j)
    if (pal_s[j] == pid) return j;
  return KINST;  // no palette match
}

// phase: 0 = all phases (cooperative, grid.sync between); 1/2/3/5/7 = split.
// nbb = blocks per batch for phases 1/5 — EXPLICIT param, identical across
// all phase dispatches (R10 bug: deriving it from gridDim broke the split
// fallback's reduce phases).
__global__ __launch_bounds__(256, 4) void k_fused(
    const float* __restrict__ pred, const float* __restrict__ targ,
    const int* __restrict__ pal, const unsigned char* __restrict__ nb_raw,
    const float* __restrict__ dw, int ndw,
    float* __restrict__ partialS, float* __restrict__ tmp2,
    float* __restrict__ sums, float4* __restrict__ A_g, float* __restrict__ W_g,
    float4* __restrict__ Z_g, float* __restrict__ cw_g, int* __restrict__ flagp,
    float* __restrict__ res_part, unsigned char* __restrict__ k0c,
    float* __restrict__ out, int B, int HW, int nbb, int phase) {
  __shared__ SmAll sm;
  const int gid = blockIdx.x, t = threadIdx.x;
  const bool coop = (phase == 0);
  const int b0 = gid / nbb, r0 = gid - b0 * nbb;
  const int nq = HW >> 2;
  const int firstq = r0 * 256 + t;
  // registers carried stats->pix (coop mode only)
  float4 cP0, cP1, cP2;
  int ck0 = KINST, ck1 = KINST, ck2 = KINST, ck3 = KINST;
  bool havec = false;

  // ============ phase 1: per-block partial histograms + k0 cache ============
  if ((phase == 0 || phase == 1) && b0 < B) {
    SmStats* S = &sm.st;
    for (int i = t; i < 4 * 4 * KINST; i += 256) (&S->ls[0][0][0])[i] = 0.f;
    for (int i = t; i < KINST; i += 256) S->pal[i] = pal[i];
    __syncthreads();
    int w = t >> 6;
    const float* tb = targ + (size_t)b0 * 3 * HW;
    const float* pb = pred + (size_t)b0 * 3 * HW;
    unsigned char* kb = k0c + (size_t)b0 * HW;
    const float4* tb4 = (const float4*)tb;
    const float4* pb4 = (const float4*)pb;
    for (int q = firstq; q < nq; q += nbb * 256) {
      float4 t0 = tb4[q], t1 = tb4[q + nq], t2 = tb4[q + 2 * nq];
      float4 p0 = pb4[q], p1 = pb4[q + nq], p2 = pb4[q + 2 * nq];
      int ka = decode_k0(t0.x, t1.x, t2.x, S->pal);
      int kc = decode_k0(t0.y, t1.y, t2.y, S->pal);
      int kd = decode_k0(t0.z, t1.z, t2.z, S->pal);
      int ke = decode_k0(t0.w, t1.w, t2.w, S->pal);
      if (coop && q == firstq) {
        cP0 = p0; cP1 = p1; cP2 = p2;
        ck0 = ka; ck1 = kc; ck2 = kd; ck3 = ke; havec = true;
      }
      if (ka < KINST) {
        atomicAdd(&S->ls[w][0][ka], p0.x); atomicAdd(&S->ls[w][1][ka], p1.x);
        atomicAdd(&S->ls[w][2][ka], p2.x); atomicAdd(&S->ls[w][3][ka], 1.f);
      }
      if (kc < KINST) {
        atomicAdd(&S->ls[w][0][kc], p0.y); atomicAdd(&S->ls[w][1][kc], p1.y);
        atomicAdd(&S->ls[w][2][kc], p2.y); atomicAdd(&S->ls[w][3][kc], 1.f);
      }
      if (kd < KINST) {
        atomicAdd(&S->ls[w][0][kd], p0.z); atomicAdd(&S->ls[w][1][kd], p1.z);
        atomicAdd(&S->ls[w][2][kd], p2.z); atomicAdd(&S->ls[w][3][kd], 1.f);
      }
      if (ke < KINST) {
        atomicAdd(&S->ls[w][0][ke], p0.w); atomicAdd(&S->ls[w][1][ke], p1.w);
        atomicAdd(&S->ls[w][2][ke], p2.w); atomicAdd(&S->ls[w][3][ke], 1.f);
      }
      *(uchar4*)(kb + 4 * (size_t)q) = make_uchar4(
          (unsigned char)ka, (unsigned char)kc, (unsigned char)kd,
          (unsigned char)ke);
    }
    for (int i = (nq << 2) + r0 * 256 + t; i < HW; i += nbb * 256) {
      int k0 = decode_k0(tb[i], tb[i + HW], tb[i + 2 * HW], S->pal);
      kb[i] = (unsigned char)k0;
      if (k0 < KINST) {
        atomicAdd(&S->ls[w][0][k0], pb[i]);
        atomicAdd(&S->ls[w][1][k0], pb[i + HW]);
        atomicAdd(&S->ls[w][2][k0], pb[i + 2 * HW]);
        atomicAdd(&S->ls[w][3][k0], 1.f);
      }
    }
    __syncthreads();
    float* o = partialS + ((size_t)b0 * nbb + r0) * 256;
    int c = t >> 6, k = t & 63;
    o[t] = S->ls[0][c][k] + S->ls[1][c][k] + S->ls[2][c][k] + S->ls[3][c][k];
  }
  if (coop) cg::this_grid().sync();

  // ============ phase 2: stage-1 reduce (B*16 blocks) ============
  if ((phase == 0 || phase == 2) && gid < B * 16) {
    int b = gid >> 4, rr = gid & 15;
    int chunk = (nbb + 15) / 16;
    int lo = rr * chunk, hi = min(lo + chunk, nbb);
    float acc = 0.f;
    for (int q2 = lo; q2 < hi; ++q2)
      acc += partialS[((size_t)b * nbb + q2) * 256 + t];
    tmp2[((size_t)b * 16 + rr) * 256 + t] = acc;
  }
  if (coop) cg::this_grid().sync();

  // ============ phase 3: stage-2 reduce + tables (B blocks) ============
  if ((phase == 0 || phase == 3) && gid < B) {
    SmRed* R = &sm.rd;
    __syncthreads();  // union reuse guard
    int b = gid;
    float acc = 0.f;
    #pragma unroll
    for (int q2 = 0; q2 < 16; ++q2)
      acc += tmp2[((size_t)b * 16 + q2) * 256 + t];
    R->red[t] = acc;
    sums[((size_t)b * KINST + (t & 63)) * 4 + (t >> 6)] = acc;
    if (t == 0) R->nu = 0;
    __syncthreads();
    {
      float d0 = dw[0];
      int nuv = 0;
      for (int x = t; x < ndw; x += 256) nuv |= (dw[x] != d0);
      if (nuv) atomicOr(&R->nu, 1);
    }
    __syncthreads();
    if (t < KINST) {
      float s0 = R->red[t], s1 = R->red[64 + t], s2 = R->red[128 + t],
            cnt = R->red[192 + t];
      float inv = cnt > 0.f ? 1.f / cnt : 0.f;
      float m0 = s0 * inv, m1 = s1 * inv, m2 = s2 * inv;
      bool isbg = (pal[t] == 0);
      bool nb = (nb_raw[b] != 0) || (nb_raw[4 * b] != 0);  // robust bool width
      float cf = (!isbg || !nb) ? 1.f : 0.f;
      float sc = (!isbg && cnt > 0.f) ? 10.f / (((float)HW - cnt) * sqrtf(cnt))
                                      : 0.f;
      A_g[b * 65 + t] = make_float4(-2.f * m0, -2.f * m1, -2.f * m2,
                                    m0 * m0 + m1 * m1 + m2 * m2 + 1.f);
      Z_g[b * 65 + t] = make_float4(isbg ? 0.f : m0, isbg ? 0.f : m1,
                                    isbg ? 0.f : m2,
                                    cnt > 0.f ? cf / (3.f * cnt) : 0.f);
      W_g[b * 65 + t] = 300.f * dw[0] * sc;
      R->scale[t] = sc;
    }
    if (t == KINST) {
      A_g[b * 65 + KINST] = make_float4(0.f, 0.f, 0.f, 1.f);
      Z_g[b * 65 + KINST] = make_float4(0.f, 0.f, 0.f, 0.f);
      W_g[b * 65 + KINST] = 0.f;
    }
    __syncthreads();
    if (t == 0) flagp[b] = R->nu;
    if (R->nu) {
      float* ct = cw_g + (size_t)b * KINST * 65;
      for (int t2 = t; t2 < KINST * 65; t2 += 256) {
        int kk = t2 / 65, j = t2 - kk * 65;
        float v = 0.f;
        if (j < KINST && j != kk) v = 300.f * dw[kk * KINST + j] * R->scale[kk];
        ct[t2] = v;
      }
    }
  }
  if (coop) cg::this_grid().sync();

  // ============ phase 5: pixel loop ============
  if ((phase == 0 || phase == 5) && b0 < B) {
    SmPix* P = &sm.px;
    __syncthreads();  // union reuse guard
    if (t < KINST + 1) {
      P->A[t] = A_g[b0 * 65 + t];
      P->Z[t] = Z_g[b0 * 65 + t];
      P->W[t] = W_g[b0 * 65 + t];
    }
    if (t < KINST) P->pal[t] = pal[t];
    if (t == 0) {
      int f = 0;
      for (int bb = 0; bb < B; ++bb) f |= flagp[bb];
      P->nonuni = f;
    }
    __syncthreads();
    bool nonuni = P->nonuni != 0;
    if (nonuni) {
      const float* cwb = cw_g + (size_t)b0 * KINST * 65;
      for (int i = t; i < KINST * 65; i += 256) (&P->cwN[0][0])[i] = cwb[i];
      __syncthreads();
    }
    const float* pb = pred + (size_t)b0 * 3 * HW;
    const float4* pb4 = (const float4*)pb;
    const unsigned char* kb = k0c + (size_t)b0 * HW;
    const uchar4* kb4 = (const uchar4*)kb;
    float intra_l = 0.f, inter_l = 0.f;
    for (int q = firstq; q < nq; q += nbb * 256) {
      float4 P0, P1, P2;
      int ka, kc, kd, ke;
      if (havec && q == firstq) {
        P0 = cP0; P1 = cP1; P2 = cP2;
        ka = ck0; kc = ck1; kd = ck2; ke = ck3;
      } else {
        P0 = pb4[q]; P1 = pb4[q + nq]; P2 = pb4[q + 2 * nq];
        uchar4 kk = kb4[q];
        ka = kk.x; kc = kk.y; kd = kk.z; ke = kk.w;
      }
      float ppa = fmaf(P0.x, P0.x, fmaf(P1.x, P1.x, P2.x * P2.x));
      float ppb = fmaf(P0.y, P0.y, fmaf(P1.y, P1.y, P2.y * P2.y));
      float ppc = fmaf(P0.z, P0.z, fmaf(P1.z, P1.z, P2.z * P2.z));
      float ppd = fmaf(P0.w, P0.w, fmaf(P1.w, P1.w, P2.w * P2.w));
      float aa = 0.f, ab = 0.f, ac = 0.f, ad = 0.f;
      if (!nonuni) {
        #pragma unroll 8
        for (int k = 0; k < KINST; ++k) {
          float4 a = P->A[k];   // uniform addr -> broadcast b128
          float wv = P->W[k];   // uniform addr -> broadcast b32
          float ra = __builtin_amdgcn_rcpf(
              ppa + fmaf(P0.x, a.x, fmaf(P1.x, a.y, fmaf(P2.x, a.z, a.w))));
          float rb = __builtin_amdgcn_rcpf(
              ppb + fmaf(P0.y, a.x, fmaf(P1.y, a.y, fmaf(P2.y, a.z, a.w))));
          float rc = __builtin_amdgcn_rcpf(
              ppc + fmaf(P0.z, a.x, fmaf(P1.z, a.y, fmaf(P2.z, a.z, a.w))));
          float rd = __builtin_amdgcn_rcpf(
              ppd + fmaf(P0.w, a.x, fmaf(P1.w, a.y, fmaf(P2.w, a.z, a.w))));
          aa = fmaf(ra, wv, aa); ab = fmaf(rb, wv, ab);
          ac = fmaf(rc, wv, ac); ad = fmaf(rd, wv, ad);
        }
        {
          float4 a = P->A[ka]; float wv = P->W[ka];
          float r = __builtin_amdgcn_rcpf(
              ppa + fmaf(P0.x, a.x, fmaf(P1.x, a.y, fmaf(P2.x, a.z, a.w))));
          aa = (ka < KINST) ? aa - wv * r : 0.f;
        }
        {
          float4 a = P->A[kc]; float wv = P->W[kc];
          float r = __builtin_amdgcn_rcpf(
              ppb + fmaf(P0.y, a.x, fmaf(P1.y, a.y, fmaf(P2.y, a.z, a.w))));
          ab = (kc < KINST) ? ab - wv * r : 0.f;
        }
        {
          float4 a = P->A[kd]; float wv = P->W[kd];
          float r = __builtin_amdgcn_rcpf(
              ppc + fmaf(P0.z, a.x, fmaf(P1.z, a.y, fmaf(P2.z, a.z, a.w))));
          ac = (kd < KINST) ? ac - wv * r : 0.f;
        }
        {
          float4 a = P->A[ke]; float wv = P->W[ke];
          float r = __builtin_amdgcn_rcpf(
              ppd + fmaf(P0.w, a.x, fmaf(P1.w, a.y, fmaf(P2.w, a.z, a.w))));
          ad = (ke < KINST) ? ad - wv * r : 0.f;
        }
      } else {
        #pragma unroll 4
        for (int k = 0; k < KINST; ++k) {
          float4 a = P->A[k];
          float ra = __builtin_amdgcn_rcpf(
              ppa + fmaf(P0.x, a.x, fmaf(P1.x, a.y, fmaf(P2.x, a.z, a.w))));
          float rb = __builtin_amdgcn_rcpf(
              ppb + fmaf(P0.y, a.x, fmaf(P1.y, a.y, fmaf(P2.y, a.z, a.w))));
          float rc = __builtin_amdgcn_rcpf(
              ppc + fmaf(P0.z, a.x, fmaf(P1.z, a.y, fmaf(P2.z, a.z, a.w))));
          float rd = __builtin_amdgcn_rcpf(
              ppd + fmaf(P0.w, a.x, fmaf(P1.w, a.y, fmaf(P2.w, a.z, a.w))));
          aa = fmaf(ra, P->cwN[k][ka], aa); ab = fmaf(rb, P->cwN[k][kc], ab);
          ac = fmaf(rc, P->cwN[k][kd], ac); ad = fmaf(rd, P->cwN[k][ke], ad);
        }
      }
      inter_l += (aa + ab) + (ac + ad);
      {
        float4 z = P->Z[ka];
        float q0 = fabsf(P0.x - z.x), q1 = fabsf(P1.x - z.y), q2 = fabsf(P2.x - z.z);
        float hp = (q0 < 1.f ? 0.5f * q0 * q0 : q0 - 0.5f) +
                   (q1 < 1.f ? 0.5f * q1 * q1 : q1 - 0.5f) +
                   (q2 < 1.f ? 0.5f * q2 * q2 : q2 - 0.5f);
        intra_l = fmaf(hp, z.w, intra_l);
      }
      {
        float4 z = P->Z[kc];
        float q0 = fabsf(P0.y - z.x), q1 = fabsf(P1.y - z.y), q2 = fabsf(P2.y - z.z);
        float hp = (q0 < 1.f ? 0.5f * q0 * q0 : q0 - 0.5f) +
                   (q1 < 1.f ? 0.5f * q1 * q1 : q1 - 0.5f) +
                   (q2 < 1.f ? 0.5f * q2 * q2 : q2 - 0.5f);
        intra_l = fmaf(hp, z.w, intra_l);
      }
      {
        float4 z = P->Z[kd];
        float q0 = fabsf(P0.z - z.x), q1 = fabsf(P1.z - z.y), q2 = fabsf(P2.z - z.z);
        float hp = (q0 < 1.f ? 0.5f * q0 * q0 : q0 - 0.5f) +
                   (q1 < 1.f ? 0.5f * q1 * q1 : q1 - 0.5f) +
                   (q2 < 1.f ? 0.5f * q2 * q2 : q2 - 0.5f);
        intra_l = fmaf(hp, z.w, intra_l);
      }
      {
        float4 z = P->Z[ke];
        float q0 = fabsf(P0.w - z.x), q1 = fabsf(P1.w - z.y), q2 = fabsf(P2.w - z.z);
        float hp = (q0 < 1.f ? 0.5f * q0 * q0 : q0 - 0.5f) +
                   (q1 < 1.f ? 0.5f * q1 * q1 : q1 - 0.5f) +
                   (q2 < 1.f ? 0.5f * q2 * q2 : q2 - 0.5f);
        intra_l = fmaf(hp, z.w, intra_l);
      }
    }
    // scalar tail pixels (HW % 4 != 0 only)
    for (int i = (nq << 2) + r0 * 256 + t; i < HW; i += nbb * 256) {
      float p0 = pb[i], p1 = pb[i + HW], p2 = pb[i + 2 * HW];
      int k0 = (int)kb[i];
      float pp = fmaf(p0, p0, fmaf(p1, p1, p2 * p2));
      float acc = 0.f;
      for (int k = 0; k < KINST; ++k) {
        float4 a = P->A[k];
        float r = __builtin_amdgcn_rcpf(
            pp + fmaf(p0, a.x, fmaf(p1, a.y, fmaf(p2, a.z, a.w))));
        float c = nonuni ? P->cwN[k][k0]
                         : ((k == k0 || k0 >= KINST) ? 0.f : P->W[k]);
        acc = fmaf(r, c, acc);
      }
      inter_l += acc;
      float4 z = P->Z[k0];
      float q0 = fabsf(p0 - z.x), q1 = fabsf(p1 - z.y), q2 = fabsf(p2 - z.z);
      float hp = (q0 < 1.f ? 0.5f * q0 * q0 : q0 - 0.5f) +
                 (q1 < 1.f ? 0.5f * q1 * q1 : q1 - 0.5f) +
                 (q2 < 1.f ? 0.5f * q2 * q2 : q2 - 0.5f);
      intra_l = fmaf(hp, z.w, intra_l);
    }
    for (int o = 32; o > 0; o >>= 1) {
      intra_l += __shfl_down(intra_l, o, 64);
      inter_l += __shfl_down(inter_l, o, 64);
    }
    int wid = t >> 6;
    if ((t & 63) == 0) { P->rA[wid] = intra_l; P->rB[wid] = inter_l; }
    __syncthreads();
    if (t == 0) {
      float a = 0.f, c = 0.f;
      for (int i = 0; i < 4; ++i) { a += P->rA[i]; c += P->rB[i]; }
      float* rp = res_part + ((size_t)b0 * nbb + r0) * 2;
      rp[0] = a; rp[1] = c;
    }
  }
  if (coop) cg::this_grid().sync();

  // ============ phase 7: final combine (block 0) ============
  if ((phase == 0 || phase == 7) && gid == 0) {
    SmFin* F = &sm.fn;
    __syncthreads();  // union reuse guard
    float total = 0.f;
    for (int b = 0; b < B; ++b) {
      __syncthreads();
      if (t < KINST) {
        float4 s = ((const float4*)sums)[b * KINST + t];
        float cnt = s.w;
        float inv = cnt > 0.f ? 1.f / cnt : 0.f;
        bool isbg = (pal[t] == 0);
        bool nb = (nb_raw[b] != 0) || (nb_raw[4 * b] != 0);
        float cf = (!isbg || !nb) ? 1.f : 0.f;
        F->zf[t] = make_float4(isbg ? 0.f : s.x * inv, isbg ? 0.f : s.y * inv,
                               isbg ? 0.f : s.z * inv, cf);
      }
      __syncthreads();
      float psum = 0.f, pcnt = 0.f, cfs = 0.f, ra = 0.f, rc = 0.f;
      for (int idx = t; idx < KINST * KINST; idx += 256) {
        int j = idx >> 6, k = idx & 63;
        if (j < k) {
          float4 a = F->zf[j], c4 = F->zf[k];
          float m = a.w * c4.w;
          float d0 = a.x - c4.x, d1 = a.y - c4.y, d2 = a.z - c4.z;
          float sqd = d0 * d0 + d1 * d1 + d2 * d2;
          psum += dw[j * KINST + k] * 300.f / (sqd + 1.f) * m;
          pcnt += m;
        }
      }
      if (t < KINST) cfs = F->zf[t].w;
      for (int bx = t; bx < nbb; bx += 256) {
        const float* rp = res_part + ((size_t)b * nbb + bx) * 2;
        ra += rp[0]; rc += rp[1];
      }
      for (int o = 32; o > 0; o >>= 1) {
        psum += __shfl_down(psum, o, 64);
        pcnt += __shfl_down(pcnt, o, 64);
        cfs += __shfl_down(cfs, o, 64);
        ra += __shfl_down(ra, o, 64);
        rc += __shfl_down(rc, o, 64);
      }
      int wid = t >> 6;
      if ((t & 63) == 0) {
        F->r[0][wid] = psum; F->r[1][wid] = pcnt; F->r[2][wid] = cfs;
        F->r[3][wid] = ra; F->r[4][wid] = rc;
      }
      __syncthreads();
      if (t == 0) {
        float ps = 0.f, pc = 0.f, cs = 0.f, sa = 0.f, sc2 = 0.f;
        for (int i = 0; i < 4; ++i) {
          ps += F->r[0][i]; pc += F->r[1][i]; cs += F->r[2][i];
          sa += F->r[3][i]; sc2 += F->r[4][i];
        }
        float mean_sep = pc > 0.f ? ps / fmaxf(pc, 1.f) : 0.f;
        float ct = fmaxf(cs, 1.f);
        total += (sa + sc2 + mean_sep) / ct;
      }
    }
    if (t == 0) out[0] = total / (float)B;
  }
}

extern "C" void kernel_launch(void* const* d_in, const int* in_sizes, int n_in,
                              void* d_out, int out_size, void* d_ws, size_t ws_size,
                              hipStream_t stream) {
  const float* pred = (const float*)d_in[0];
  const float* targ = (const float*)d_in[1];
  const unsigned char* nb = (const unsigned char*)d_in[2];
  const float* dw = (const float*)d_in[3];
  const int* pal = (const int*)d_in[4];
  int B = in_sizes[2];                 // 4
  int ndw = in_sizes[3];               // 4096
  int HW = in_sizes[0] / (3 * B);      // 262144  (kernels assume K==64)

  // size the coop grid from the occupancy API (R10 assumed 4 blocks/CU)
  int blocksPerCU = 0;
  hipError_t qe = hipOccupancyMaxActiveBlocksPerMultiprocessor(
      &blocksPerCU, (const void*)k_fused, 256, 0);
  int numCU = 256;
  {
    int dev = 0;
    if (hipGetDevice(&dev) == hipSuccess) {
      hipDeviceProp_t props;
      if (hipGetDeviceProperties(&props, dev) == hipSuccess)
        numCU = props.multiProcessorCount;
    }
  }
  bool try_coop = (qe == hipSuccess && blocksPerCU > 0);
  int maxCoop = try_coop ? blocksPerCU * numCU : 1024;
  int GRID = maxCoop < 1024 ? maxCoop : 1024;
  GRID -= GRID % B;                    // exact b partition
  if (GRID < B * 16) { GRID = B * 16; try_coop = false; }
  int nbb = GRID / B;

  // ws layout (floats):
  float* partialS = (float*)d_ws;                               // B*nbb*256
  float* tmp2 = partialS + (size_t)B * nbb * 256;               // B*16*256
  float* sums = tmp2 + (size_t)B * 16 * 256;                    // B*256
  float4* A_g = (float4*)(sums + (size_t)B * 256);              // B*65
  float* W_g = (float*)(A_g + (size_t)B * 65);                  // B*65
  float4* Z_g = (float4*)(W_g + (size_t)B * 65);                // B*65
  float* cw_g = (float*)(Z_g + (size_t)B * 65);                 // B*64*65
  float* res_part = cw_g + (size_t)B * KINST * 65;              // B*nbb*2
  int* flagp = (int*)(res_part + (size_t)B * nbb * 2);          // B
  unsigned char* k0c = (unsigned char*)(flagp + B);             // B*HW bytes

  float* out = (float*)d_out;
  int phase = 0;
  void* args[] = {&pred, &targ, &pal, &nb, &dw, &ndw, &partialS, &tmp2,
                  &sums, &A_g, &W_g, &Z_g, &cw_g, &flagp, &res_part, &k0c,
                  &out, &B, &HW, &nbb, &phase};
  hipError_t e = hipErrorUnknown;
  if (try_coop)
    e = hipLaunchCooperativeKernel((void*)k_fused, dim3(GRID), dim3(256), args,
                                   0, stream);
  if (e != hipSuccess) {
    (void)hipGetLastError();  // clear sticky state from the failed coop launch
    // split fallback: same kernel, one phase per dispatch, SAME nbb everywhere
    k_fused<<<GRID, 256, 0, stream>>>(pred, targ, pal, nb, dw, ndw, partialS,
                                      tmp2, sums, A_g, W_g, Z_g, cw_g, flagp,
                                      res_part, k0c, out, B, HW, nbb, 1);
    k_fused<<<B * 16, 256, 0, stream>>>(pred, targ, pal, nb, dw, ndw, partialS,
                                        tmp2, sums, A_g, W_g, Z_g, cw_g, flagp,
                                        res_part, k0c, out, B, HW, nbb, 2);
    k_fused<<<B, 256, 0, stream>>>(pred, targ, pal, nb, dw, ndw, partialS,
                                   tmp2, sums, A_g, W_g, Z_g, cw_g, flagp,
                                   res_part, k0c, out, B, HW, nbb, 3);
    k_fused<<<GRID, 256, 0, stream>>>(pred, targ, pal, nb, dw, ndw, partialS,
                                      tmp2, sums, A_g, W_g, Z_g, cw_g, flagp,
                                      res_part, k0c, out, B, HW, nbb, 5);
    k_fused<<<1, 256, 0, stream>>>(pred, targ, pal, nb, dw, ndw, partialS,
                                   tmp2, sums, A_g, W_g, Z_g, cw_g, flagp,
                                   res_part, k0c, out, B, HW, nbb, 7);
  }
}

// Round 12
// 190.790 us; speedup vs baseline: 1.4202x; 1.4202x over previous
//
#include <hip/hip_runtime.h>

#define KINST 64
#define NBS 128   // kernel-A blocks per batch
#define GXP 256   // kernel-B blocks per batch

__device__ __forceinline__ int decode_k0(float t0, float t1, float t2,
                                         const int* pal_s) {
  int pid = (int)(fmaf(t0, 65536.f, fmaf(t1, 256.f, t2)) + 0.5f);
  if (pid >= 0 && pid < KINST && pal_s[pid] == pid) return pid;  // fast path
  for (int j = 0; j < KINST; ++j)
    if (pal_s[j] == pid) return j;
  return KINST;  // no palette match
}

// ---------------------------------------------------------------------------
// Kernel A: per-block partial histograms (R7 body) + LAST BLOCK reduces the
// partials and builds all per-(b,k) tables in its tail (no extra dispatch).
// ---------------------------------------------------------------------------
__global__ __launch_bounds__(256) void kA(
    const float* __restrict__ pred, const float* __restrict__ targ,
    const int* __restrict__ pal, const unsigned char* __restrict__ nb_raw,
    const float* __restrict__ dw, int ndw,
    float* __restrict__ partialS, float* __restrict__ sums,
    float4* __restrict__ A_g, float* __restrict__ W_g, float4* __restrict__ Z_g,
    float* __restrict__ cw_g, int* __restrict__ flagp,
    unsigned char* __restrict__ k0c, int* __restrict__ ctr, int B, int HW) {
  int b = blockIdx.y, r = blockIdx.x, t = threadIdx.x;
  int nbs = gridDim.x;
  __shared__ float ls[4][4][KINST];  // [wave][component][k]
  __shared__ int pal_s[KINST];
  __shared__ int lastf, nu_sh;
  for (int i = t; i < 4 * 4 * KINST; i += 256) (&ls[0][0][0])[i] = 0.f;
  for (int i = t; i < KINST; i += 256) pal_s[i] = pal[i];
  __syncthreads();
  int w = t >> 6;
  const float* tb = targ + (size_t)b * 3 * HW;
  const float* pb = pred + (size_t)b * 3 * HW;
  unsigned char* kb = k0c ? k0c + (size_t)b * HW : nullptr;
  int nq = HW >> 2;
  const float4* tb4 = (const float4*)tb;
  const float4* pb4 = (const float4*)pb;
  for (int q = r * 256 + t; q < nq; q += nbs * 256) {
    float4 t0 = tb4[q], t1 = tb4[q + nq], t2 = tb4[q + 2 * nq];
    float4 p0 = pb4[q], p1 = pb4[q + nq], p2 = pb4[q + 2 * nq];
    int ka = decode_k0(t0.x, t1.x, t2.x, pal_s);
    int kc = decode_k0(t0.y, t1.y, t2.y, pal_s);
    int kd = decode_k0(t0.z, t1.z, t2.z, pal_s);
    int ke = decode_k0(t0.w, t1.w, t2.w, pal_s);
    if (ka < KINST) {
      atomicAdd(&ls[w][0][ka], p0.x); atomicAdd(&ls[w][1][ka], p1.x);
      atomicAdd(&ls[w][2][ka], p2.x); atomicAdd(&ls[w][3][ka], 1.f);
    }
    if (kc < KINST) {
      atomicAdd(&ls[w][0][kc], p0.y); atomicAdd(&ls[w][1][kc], p1.y);
      atomicAdd(&ls[w][2][kc], p2.y); atomicAdd(&ls[w][3][kc], 1.f);
    }
    if (kd < KINST) {
      atomicAdd(&ls[w][0][kd], p0.z); atomicAdd(&ls[w][1][kd], p1.z);
      atomicAdd(&ls[w][2][kd], p2.z); atomicAdd(&ls[w][3][kd], 1.f);
    }
    if (ke < KINST) {
      atomicAdd(&ls[w][0][ke], p0.w); atomicAdd(&ls[w][1][ke], p1.w);
      atomicAdd(&ls[w][2][ke], p2.w); atomicAdd(&ls[w][3][ke], 1.f);
    }
    if (kb)
      *(uchar4*)(kb + 4 * (size_t)q) = make_uchar4(
          (unsigned char)ka, (unsigned char)kc, (unsigned char)kd,
          (unsigned char)ke);
  }
  for (int i = (nq << 2) + r * 256 + t; i < HW; i += nbs * 256) {
    int k0 = decode_k0(tb[i], tb[i + HW], tb[i + 2 * HW], pal_s);
    if (kb) kb[i] = (unsigned char)k0;
    if (k0 < KINST) {
      atomicAdd(&ls[w][0][k0], pb[i]); atomicAdd(&ls[w][1][k0], pb[i + HW]);
      atomicAdd(&ls[w][2][k0], pb[i + 2 * HW]); atomicAdd(&ls[w][3][k0], 1.f);
    }
  }
  __syncthreads();
  {
    float* o = partialS + ((size_t)b * nbs + r) * 256;
    int c = t >> 6, k = t & 63;
    o[t] = ls[0][c][k] + ls[1][c][k] + ls[2][c][k] + ls[3][c][k];
  }
  // ---- last-block-done: reduce + tables (deterministic fixed-order) ----
  __threadfence();
  if (t == 0) {
    int d = atomicAdd(ctr, 1);
    lastf = (d == (int)(gridDim.x * gridDim.y) - 1);
  }
  __syncthreads();
  if (!lastf) return;
  __threadfence();
  if (t == 0) nu_sh = 0;
  __syncthreads();
  {
    float d0 = dw[0];
    int nuv = 0;
    for (int x = t; x < ndw; x += 256) nuv |= (dw[x] != d0);
    if (nuv) atomicOr(&nu_sh, 1);
  }
  __syncthreads();
  if (t == 0) flagp[0] = nu_sh;
  float* red = &ls[0][0][0];       // reuse histogram LDS
  float* scale_sh = red + 256;
  for (int bb = 0; bb < B; ++bb) {
    const float* src = partialS + (size_t)bb * nbs * 256;
    float s0 = 0.f, s1 = 0.f, s2 = 0.f, s3 = 0.f;
    float s4 = 0.f, s5 = 0.f, s6 = 0.f, s7 = 0.f;
    int j = 0;
    for (; j + 8 <= nbs; j += 8) {
      s0 += src[(size_t)(j + 0) * 256 + t];
      s1 += src[(size_t)(j + 1) * 256 + t];
      s2 += src[(size_t)(j + 2) * 256 + t];
      s3 += src[(size_t)(j + 3) * 256 + t];
      s4 += src[(size_t)(j + 4) * 256 + t];
      s5 += src[(size_t)(j + 5) * 256 + t];
      s6 += src[(size_t)(j + 6) * 256 + t];
      s7 += src[(size_t)(j + 7) * 256 + t];
    }
    for (; j < nbs; ++j) s0 += src[(size_t)j * 256 + t];
    float acc = ((s0 + s1) + (s2 + s3)) + ((s4 + s5) + (s6 + s7));
    red[t] = acc;
    sums[((size_t)bb * KINST + (t & 63)) * 4 + (t >> 6)] = acc;
    __syncthreads();
    if (t < KINST) {
      float m0s = red[t], m1s = red[64 + t], m2s = red[128 + t],
            cnt = red[192 + t];
      float inv = cnt > 0.f ? 1.f / cnt : 0.f;
      float m0 = m0s * inv, m1 = m1s * inv, m2 = m2s * inv;
      bool isbg = (pal[t] == 0);
      bool nbv = (nb_raw[bb] != 0) || (nb_raw[4 * bb] != 0);  // robust width
      float cf = (!isbg || !nbv) ? 1.f : 0.f;
      float sc = (!isbg && cnt > 0.f) ? 10.f / (((float)HW - cnt) * sqrtf(cnt))
                                      : 0.f;
      A_g[bb * 65 + t] = make_float4(-2.f * m0, -2.f * m1, -2.f * m2,
                                     m0 * m0 + m1 * m1 + m2 * m2 + 1.f);
      Z_g[bb * 65 + t] = make_float4(isbg ? 0.f : m0, isbg ? 0.f : m1,
                                     isbg ? 0.f : m2,
                                     cnt > 0.f ? cf / (3.f * cnt) : 0.f);
      W_g[bb * 65 + t] = 300.f * dw[0] * sc;
      scale_sh[t] = sc;
    }
    if (t == KINST) {
      A_g[bb * 65 + KINST] = make_float4(0.f, 0.f, 0.f, 1.f);
      Z_g[bb * 65 + KINST] = make_float4(0.f, 0.f, 0.f, 0.f);
      W_g[bb * 65 + KINST] = 0.f;
    }
    __syncthreads();
    if (nu_sh) {
      float* ct = cw_g + (size_t)bb * KINST * 65;
      for (int t2 = t; t2 < KINST * 65; t2 += 256) {
        int kk = t2 / 65, jj = t2 - kk * 65;
        float v = 0.f;
        if (jj < KINST && jj != kk)
          v = 300.f * dw[kk * KINST + jj] * scale_sh[kk];
        ct[t2] = v;
      }
    }
    __syncthreads();  // red/scale_sh reuse guard for next bb
  }
}

// ---------------------------------------------------------------------------
// Kernel B: pixel loop (R7 body: LDS tables, 4 px/thread) + LAST BLOCK does
// the final combine in its tail.
// ---------------------------------------------------------------------------
template <bool USE_CACHE>
__global__ __launch_bounds__(256) void kB(
    const float* __restrict__ pred, const float* __restrict__ targ,
    const unsigned char* __restrict__ k0c, const int* __restrict__ pal,
    const unsigned char* __restrict__ nb_raw, const float* __restrict__ dw,
    const float* __restrict__ sums, const float4* __restrict__ A_g,
    const float* __restrict__ W_g, const float4* __restrict__ Z_g,
    const float* __restrict__ cw_g, const int* __restrict__ flagp,
    float* __restrict__ res_part, int* __restrict__ ctr,
    float* __restrict__ out, int B, int HW) {
  int b = blockIdx.y, r = blockIdx.x, t = threadIdx.x;
  int gx = gridDim.x;
  __shared__ float4 A_s[KINST + 1];
  __shared__ float4 Z_s[KINST + 1];
  __shared__ float W_s[KINST + 1];
  __shared__ float cwN[KINST][KINST + 1];
  __shared__ int pal_s[KINST];
  __shared__ int nonuni_s, lastf;
  __shared__ float rA[4], rB_[4];
  if (t < KINST + 1) {
    A_s[t] = A_g[b * 65 + t];
    Z_s[t] = Z_g[b * 65 + t];
    W_s[t] = W_g[b * 65 + t];
  }
  if (!USE_CACHE && t < KINST) pal_s[t] = pal[t];
  if (t == 0) nonuni_s = flagp[0];
  __syncthreads();
  bool nonuni = nonuni_s != 0;
  if (nonuni) {
    const float* cwb = cw_g + (size_t)b * KINST * 65;
    for (int i = t; i < KINST * 65; i += 256) (&cwN[0][0])[i] = cwb[i];
    __syncthreads();
  }
  const float* pb = pred + (size_t)b * 3 * HW;
  const float* tb = targ + (size_t)b * 3 * HW;
  const float4* pb4 = (const float4*)pb;
  const float4* tb4 = (const float4*)tb;
  int nq = HW >> 2;
  const uchar4* kb4 = USE_CACHE ? (const uchar4*)(k0c + (size_t)b * HW) : nullptr;
  float intra_l = 0.f, inter_l = 0.f;
  for (int q = r * 256 + t; q < nq; q += gx * 256) {
    float4 P0 = pb4[q], P1 = pb4[q + nq], P2 = pb4[q + 2 * nq];
    int ka, kc, kd, ke;
    if (USE_CACHE) {
      uchar4 kk = kb4[q];
      ka = kk.x; kc = kk.y; kd = kk.z; ke = kk.w;
    } else {
      float4 T0 = tb4[q], T1 = tb4[q + nq], T2 = tb4[q + 2 * nq];
      ka = decode_k0(T0.x, T1.x, T2.x, pal_s);
      kc = decode_k0(T0.y, T1.y, T2.y, pal_s);
      kd = decode_k0(T0.z, T1.z, T2.z, pal_s);
      ke = decode_k0(T0.w, T1.w, T2.w, pal_s);
    }
    float ppa = fmaf(P0.x, P0.x, fmaf(P1.x, P1.x, P2.x * P2.x));
    float ppb = fmaf(P0.y, P0.y, fmaf(P1.y, P1.y, P2.y * P2.y));
    float ppc = fmaf(P0.z, P0.z, fmaf(P1.z, P1.z, P2.z * P2.z));
    float ppd = fmaf(P0.w, P0.w, fmaf(P1.w, P1.w, P2.w * P2.w));
    float aa = 0.f, ab = 0.f, ac = 0.f, ad = 0.f;
    if (!nonuni) {
      #pragma unroll 8
      for (int k = 0; k < KINST; ++k) {
        float4 a = A_s[k];          // uniform addr -> broadcast b128
        float wv = W_s[k];          // uniform addr -> broadcast b32
        float ra = __builtin_amdgcn_rcpf(
            ppa + fmaf(P0.x, a.x, fmaf(P1.x, a.y, fmaf(P2.x, a.z, a.w))));
        float rb = __builtin_amdgcn_rcpf(
            ppb + fmaf(P0.y, a.x, fmaf(P1.y, a.y, fmaf(P2.y, a.z, a.w))));
        float rc = __builtin_amdgcn_rcpf(
            ppc + fmaf(P0.z, a.x, fmaf(P1.z, a.y, fmaf(P2.z, a.z, a.w))));
        float rd = __builtin_amdgcn_rcpf(
            ppd + fmaf(P0.w, a.x, fmaf(P1.w, a.y, fmaf(P2.w, a.z, a.w))));
        aa = fmaf(ra, wv, aa); ab = fmaf(rb, wv, ab);
        ac = fmaf(rc, wv, ac); ad = fmaf(rd, wv, ad);
      }
      {  // diagonal subtract + invalid mask
        float4 a = A_s[ka]; float wv = W_s[ka];
        float rr = __builtin_amdgcn_rcpf(
            ppa + fmaf(P0.x, a.x, fmaf(P1.x, a.y, fmaf(P2.x, a.z, a.w))));
        aa = (ka < KINST) ? aa - wv * rr : 0.f;
      }
      {
        float4 a = A_s[kc]; float wv = W_s[kc];
        float rr = __builtin_amdgcn_rcpf(
            ppb + fmaf(P0.y, a.x, fmaf(P1.y, a.y, fmaf(P2.y, a.z, a.w))));
        ab = (kc < KINST) ? ab - wv * rr : 0.f;
      }
      {
        float4 a = A_s[kd]; float wv = W_s[kd];
        float rr = __builtin_amdgcn_rcpf(
            ppc + fmaf(P0.z, a.x, fmaf(P1.z, a.y, fmaf(P2.z, a.z, a.w))));
        ac = (kd < KINST) ? ac - wv * rr : 0.f;
      }
      {
        float4 a = A_s[ke]; float wv = W_s[ke];
        float rr = __builtin_amdgcn_rcpf(
            ppd + fmaf(P0.w, a.x, fmaf(P1.w, a.y, fmaf(P2.w, a.z, a.w))));
        ad = (ke < KINST) ? ad - wv * rr : 0.f;
      }
    } else {
      #pragma unroll 4
      for (int k = 0; k < KINST; ++k) {
        float4 a = A_s[k];
        float ra = __builtin_amdgcn_rcpf(
            ppa + fmaf(P0.x, a.x, fmaf(P1.x, a.y, fmaf(P2.x, a.z, a.w))));
        float rb = __builtin_amdgcn_rcpf(
            ppb + fmaf(P0.y, a.x, fmaf(P1.y, a.y, fmaf(P2.y, a.z, a.w))));
        float rc = __builtin_amdgcn_rcpf(
            ppc + fmaf(P0.z, a.x, fmaf(P1.z, a.y, fmaf(P2.z, a.z, a.w))));
        float rd = __builtin_amdgcn_rcpf(
            ppd + fmaf(P0.w, a.x, fmaf(P1.w, a.y, fmaf(P2.w, a.z, a.w))));
        aa = fmaf(ra, cwN[k][ka], aa); ab = fmaf(rb, cwN[k][kc], ab);
        ac = fmaf(rc, cwN[k][kd], ac); ad = fmaf(rd, cwN[k][ke], ad);
      }
    }
    inter_l += (aa + ab) + (ac + ad);
    {
      float4 z = Z_s[ka];
      float q0 = fabsf(P0.x - z.x), q1 = fabsf(P1.x - z.y), q2 = fabsf(P2.x - z.z);
      float hp = (q0 < 1.f ? 0.5f * q0 * q0 : q0 - 0.5f) +
                 (q1 < 1.f ? 0.5f * q1 * q1 : q1 - 0.5f) +
                 (q2 < 1.f ? 0.5f * q2 * q2 : q2 - 0.5f);
      intra_l = fmaf(hp, z.w, intra_l);
    }
    {
      float4 z = Z_s[kc];
      float q0 = fabsf(P0.y - z.x), q1 = fabsf(P1.y - z.y), q2 = fabsf(P2.y - z.z);
      float hp = (q0 < 1.f ? 0.5f * q0 * q0 : q0 - 0.5f) +
                 (q1 < 1.f ? 0.5f * q1 * q1 : q1 - 0.5f) +
                 (q2 < 1.f ? 0.5f * q2 * q2 : q2 - 0.5f);
      intra_l = fmaf(hp, z.w, intra_l);
    }
    {
      float4 z = Z_s[kd];
      float q0 = fabsf(P0.z - z.x), q1 = fabsf(P1.z - z.y), q2 = fabsf(P2.z - z.z);
      float hp = (q0 < 1.f ? 0.5f * q0 * q0 : q0 - 0.5f) +
                 (q1 < 1.f ? 0.5f * q1 * q1 : q1 - 0.5f) +
                 (q2 < 1.f ? 0.5f * q2 * q2 : q2 - 0.5f);
      intra_l = fmaf(hp, z.w, intra_l);
    }
    {
      float4 z = Z_s[ke];
      float q0 = fabsf(P0.w - z.x), q1 = fabsf(P1.w - z.y), q2 = fabsf(P2.w - z.z);
      float hp = (q0 < 1.f ? 0.5f * q0 * q0 : q0 - 0.5f) +
                 (q1 < 1.f ? 0.5f * q1 * q1 : q1 - 0.5f) +
                 (q2 < 1.f ? 0.5f * q2 * q2 : q2 - 0.5f);
      intra_l = fmaf(hp, z.w, intra_l);
    }
  }
  // scalar tail (HW % 4 != 0 only)
  for (int i = (nq << 2) + r * 256 + t; i < HW; i += gx * 256) {
    float p0 = pb[i], p1 = pb[i + HW], p2 = pb[i + 2 * HW];
    int k0 = USE_CACHE ? (int)k0c[(size_t)b * HW + i]
                       : decode_k0(tb[i], tb[i + HW], tb[i + 2 * HW], pal_s);
    float pp = fmaf(p0, p0, fmaf(p1, p1, p2 * p2));
    float acc = 0.f;
    for (int k = 0; k < KINST; ++k) {
      float4 a = A_s[k];
      float rr = __builtin_amdgcn_rcpf(
          pp + fmaf(p0, a.x, fmaf(p1, a.y, fmaf(p2, a.z, a.w))));
      float c = nonuni ? cwN[k][k0]
                       : ((k == k0 || k0 >= KINST) ? 0.f : W_s[k]);
      acc = fmaf(rr, c, acc);
    }
    inter_l += acc;
    float4 z = Z_s[k0];
    float q0 = fabsf(p0 - z.x), q1 = fabsf(p1 - z.y), q2 = fabsf(p2 - z.z);
    float hp = (q0 < 1.f ? 0.5f * q0 * q0 : q0 - 0.5f) +
               (q1 < 1.f ? 0.5f * q1 * q1 : q1 - 0.5f) +
               (q2 < 1.f ? 0.5f * q2 * q2 : q2 - 0.5f);
    intra_l = fmaf(hp, z.w, intra_l);
  }
  for (int o = 32; o > 0; o >>= 1) {
    intra_l += __shfl_down(intra_l, o, 64);
    inter_l += __shfl_down(inter_l, o, 64);
  }
  int wid = t >> 6;
  if ((t & 63) == 0) { rA[wid] = intra_l; rB_[wid] = inter_l; }
  __syncthreads();
  if (t == 0) {
    float a = 0.f, c = 0.f;
    for (int i = 0; i < 4; ++i) { a += rA[i]; c += rB_[i]; }
    float* rp = res_part + ((size_t)b * gx + r) * 2;
    rp[0] = a; rp[1] = c;  // plain store
  }
  // ---- last-block-done: final combine ----
  __threadfence();
  if (t == 0) {
    int d = atomicAdd(ctr, 1);
    lastf = (d == (int)(gridDim.x * gridDim.y) - 1);
  }
  __syncthreads();
  if (!lastf) return;
  __threadfence();
  float4* zf = A_s;                       // LDS reuse
  float (*rr5)[4] = (float (*)[4])W_s;    // 5x4 floats
  float total = 0.f;
  for (int bb = 0; bb < B; ++bb) {
    __syncthreads();
    if (t < KINST) {
      float4 s = ((const float4*)sums)[bb * KINST + t];
      float cnt = s.w;
      float inv = cnt > 0.f ? 1.f / cnt : 0.f;
      bool isbg = (pal[t] == 0);
      bool nbv = (nb_raw[bb] != 0) || (nb_raw[4 * bb] != 0);
      float cf = (!isbg || !nbv) ? 1.f : 0.f;
      zf[t] = make_float4(isbg ? 0.f : s.x * inv, isbg ? 0.f : s.y * inv,
                          isbg ? 0.f : s.z * inv, cf);
    }
    __syncthreads();
    float psum = 0.f, pcnt = 0.f, cfs = 0.f, ra = 0.f, rc = 0.f;
    for (int idx = t; idx < KINST * KINST; idx += 256) {
      int j = idx >> 6, k = idx & 63;
      if (j < k) {
        float4 a = zf[j], c4 = zf[k];
        float m = a.w * c4.w;
        float d0 = a.x - c4.x, d1 = a.y - c4.y, d2 = a.z - c4.z;
        float sqd = d0 * d0 + d1 * d1 + d2 * d2;
        psum += dw[j * KINST + k] * 300.f / (sqd + 1.f) * m;
        pcnt += m;
      }
    }
    if (t < KINST) cfs = zf[t].w;
    for (int bx = t; bx < gx; bx += 256) {
      const float* rp = res_part + ((size_t)bb * gx + bx) * 2;
      ra += rp[0]; rc += rp[1];
    }
    for (int o = 32; o > 0; o >>= 1) {
      psum += __shfl_down(psum, o, 64);
      pcnt += __shfl_down(pcnt, o, 64);
      cfs += __shfl_down(cfs, o, 64);
      ra += __shfl_down(ra, o, 64);
      rc += __shfl_down(rc, o, 64);
    }
    if ((t & 63) == 0) {
      rr5[0][wid] = psum; rr5[1][wid] = pcnt; rr5[2][wid] = cfs;
      rr5[3][wid] = ra; rr5[4][wid] = rc;
    }
    __syncthreads();
    if (t == 0) {
      float ps = 0.f, pc = 0.f, cs = 0.f, sa = 0.f, sc2 = 0.f;
      for (int i = 0; i < 4; ++i) {
        ps += rr5[0][i]; pc += rr5[1][i]; cs += rr5[2][i];
        sa += rr5[3][i]; sc2 += rr5[4][i];
      }
      float mean_sep = pc > 0.f ? ps / fmaxf(pc, 1.f) : 0.f;
      float ct = fmaxf(cs, 1.f);
      total += (sa + sc2 + mean_sep) / ct;
    }
  }
  if (t == 0) out[0] = total / (float)B;
}

extern "C" void kernel_launch(void* const* d_in, const int* in_sizes, int n_in,
                              void* d_out, int out_size, void* d_ws, size_t ws_size,
                              hipStream_t stream) {
  const float* pred = (const float*)d_in[0];
  const float* targ = (const float*)d_in[1];
  const unsigned char* nb = (const unsigned char*)d_in[2];
  const float* dw = (const float*)d_in[3];
  const int* pal = (const int*)d_in[4];
  int B = in_sizes[2];                 // 4
  int ndw = in_sizes[3];               // 4096
  int HW = in_sizes[0] / (3 * B);      // 262144  (kernels assume K==64)

  // ws layout (float units; float4 arrays kept 16B-aligned):
  float* partialS = (float*)d_ws;                               // B*NBS*256
  float* sums = partialS + (size_t)B * NBS * 256;               // B*256
  float4* A_g = (float4*)(sums + (size_t)B * 256);              // B*65 f4
  float4* Z_g = A_g + (size_t)B * 65;                           // B*65 f4
  float* W_g = (float*)(Z_g + (size_t)B * 65);                  // B*65
  float* cw_g = W_g + (size_t)B * 65;                           // B*64*65
  float* res_part = cw_g + (size_t)B * KINST * 65;              // B*GXP*2
  int* flagp = (int*)(res_part + (size_t)B * GXP * 2);          // 1
  int* ctr = flagp + 1;                                         // 2
  unsigned char* k0c = (unsigned char*)(ctr + 2);               // B*HW bytes
  size_t base_bytes = (size_t)((float*)k0c - (float*)d_ws) * 4;
  bool use_cache = ws_size >= base_bytes + (size_t)B * HW;
  if (!use_cache) k0c = nullptr;

  hipMemsetAsync(ctr, 0, 2 * sizeof(int), stream);
  kA<<<dim3(NBS, B), 256, 0, stream>>>(pred, targ, pal, nb, dw, ndw, partialS,
                                       sums, A_g, W_g, Z_g, cw_g, flagp, k0c,
                                       ctr, B, HW);
  if (use_cache)
    kB<true><<<dim3(GXP, B), 256, 0, stream>>>(pred, targ, k0c, pal, nb, dw,
                                               sums, A_g, W_g, Z_g, cw_g, flagp,
                                               res_part, ctr + 1,
                                               (float*)d_out, B, HW);
  else
    kB<false><<<dim3(GXP, B), 256, 0, stream>>>(pred, targ, k0c, pal, nb, dw,
                                                sums, A_g, W_g, Z_g, cw_g, flagp,
                                                res_part, ctr + 1,
                                                (float*)d_out, B, HW);
}

// Round 13
// 60.179 us; speedup vs baseline: 4.5027x; 3.1704x over previous
//
#include <hip/hip_runtime.h>

#define KINST 64

__device__ __forceinline__ int decode_k0(float t0, float t1, float t2,
                                         const int* pal_s) {
  int pid = (int)(fmaf(t0, 65536.f, fmaf(t1, 256.f, t2)) + 0.5f);
  if (pid >= 0 && pid < KINST && pal_s[pid] == pid) return pid;  // fast path
  for (int j = 0; j < KINST; ++j)
    if (pal_s[j] == pid) return j;
  return KINST;  // no palette match
}

// ---------------------------------------------------------------------------
// Pass 1 (R7 body): per-(b,block) PARTIAL histograms via LDS atomics; plain
// coalesced stores. partialS: [B][nbs][256], index i = c*64+k.
// ---------------------------------------------------------------------------
__global__ __launch_bounds__(256) void k_stats(const float* __restrict__ pred,
                                               const float* __restrict__ targ,
                                               const int* __restrict__ pal,
                                               float* __restrict__ partialS,
                                               unsigned char* __restrict__ k0c,
                                               int HW) {
  int b = blockIdx.y;
  __shared__ float ls[4][4][KINST];  // [wave][component][k]
  __shared__ int pal_s[KINST];
  for (int i = threadIdx.x; i < 4 * 4 * KINST; i += blockDim.x)
    (&ls[0][0][0])[i] = 0.f;
  for (int i = threadIdx.x; i < KINST; i += blockDim.x) pal_s[i] = pal[i];
  __syncthreads();
  int w = threadIdx.x >> 6;
  const float* tb = targ + (size_t)b * 3 * HW;
  const float* pb = pred + (size_t)b * 3 * HW;
  unsigned char* kb = k0c ? k0c + (size_t)b * HW : nullptr;
  int nq = HW >> 2;
  const float4* tb4 = (const float4*)tb;
  const float4* pb4 = (const float4*)pb;
  for (int q = blockIdx.x * blockDim.x + threadIdx.x; q < nq;
       q += gridDim.x * blockDim.x) {
    float4 t0 = tb4[q], t1 = tb4[q + nq], t2 = tb4[q + 2 * nq];
    float4 p0 = pb4[q], p1 = pb4[q + nq], p2 = pb4[q + 2 * nq];
    int ka = decode_k0(t0.x, t1.x, t2.x, pal_s);
    int kc = decode_k0(t0.y, t1.y, t2.y, pal_s);
    int kd = decode_k0(t0.z, t1.z, t2.z, pal_s);
    int ke = decode_k0(t0.w, t1.w, t2.w, pal_s);
    if (ka < KINST) {
      atomicAdd(&ls[w][0][ka], p0.x); atomicAdd(&ls[w][1][ka], p1.x);
      atomicAdd(&ls[w][2][ka], p2.x); atomicAdd(&ls[w][3][ka], 1.f);
    }
    if (kc < KINST) {
      atomicAdd(&ls[w][0][kc], p0.y); atomicAdd(&ls[w][1][kc], p1.y);
      atomicAdd(&ls[w][2][kc], p2.y); atomicAdd(&ls[w][3][kc], 1.f);
    }
    if (kd < KINST) {
      atomicAdd(&ls[w][0][kd], p0.z); atomicAdd(&ls[w][1][kd], p1.z);
      atomicAdd(&ls[w][2][kd], p2.z); atomicAdd(&ls[w][3][kd], 1.f);
    }
    if (ke < KINST) {
      atomicAdd(&ls[w][0][ke], p0.w); atomicAdd(&ls[w][1][ke], p1.w);
      atomicAdd(&ls[w][2][ke], p2.w); atomicAdd(&ls[w][3][ke], 1.f);
    }
    if (kb) {
      uchar4 kk = make_uchar4((unsigned char)ka, (unsigned char)kc,
                              (unsigned char)kd, (unsigned char)ke);
      *(uchar4*)(kb + 4 * (size_t)q) = kk;
    }
  }
  // scalar tail (HW % 4 != 0 only)
  for (int i = (nq << 2) + blockIdx.x * blockDim.x + threadIdx.x; i < HW;
       i += gridDim.x * blockDim.x) {
    int k0 = decode_k0(tb[i], tb[i + HW], tb[i + 2 * HW], pal_s);
    if (kb) kb[i] = (unsigned char)k0;
    if (k0 < KINST) {
      atomicAdd(&ls[w][0][k0], pb[i]); atomicAdd(&ls[w][1][k0], pb[i + HW]);
      atomicAdd(&ls[w][2][k0], pb[i + 2 * HW]); atomicAdd(&ls[w][3][k0], 1.f);
    }
  }
  __syncthreads();
  float* out = partialS + ((size_t)b * gridDim.x + blockIdx.x) * 256;
  int i = threadIdx.x;  // i = c*64+k
  int c = i >> 6, k = i & 63;
  out[i] = ls[0][c][k] + ls[1][c][k] + ls[2][c][k] + ls[3][c][k];
}

// ---------------------------------------------------------------------------
// Pass 2 (grid=B): reduce partials (unroll 8, independent accumulators ->
// half the dependent latency rounds of R7) -> sums + per-(b,k) tables + flag.
// ---------------------------------------------------------------------------
__global__ __launch_bounds__(256) void k_reduce(const float* __restrict__ partialS,
                                                const float* __restrict__ dw,
                                                const int* __restrict__ pal,
                                                const unsigned char* __restrict__ nb_raw,
                                                int ndw, int nbs,
                                                float* __restrict__ sums,
                                                float4* __restrict__ A_g,
                                                float* __restrict__ W_g,
                                                float4* __restrict__ Z_g,
                                                float* __restrict__ cw_g,
                                                int* __restrict__ flagp,
                                                int B, int HW) {
  int b = blockIdx.x;
  int i = threadIdx.x;
  __shared__ float red[256];
  __shared__ float scale_sh[KINST];
  __shared__ int nu_sh;
  const float* src = partialS + (size_t)b * nbs * 256;
  float s0 = 0.f, s1 = 0.f, s2 = 0.f, s3 = 0.f;
  float s4 = 0.f, s5 = 0.f, s6 = 0.f, s7 = 0.f;
  int bx = 0;
  for (; bx + 8 <= nbs; bx += 8) {
    s0 += src[(size_t)(bx + 0) * 256 + i];
    s1 += src[(size_t)(bx + 1) * 256 + i];
    s2 += src[(size_t)(bx + 2) * 256 + i];
    s3 += src[(size_t)(bx + 3) * 256 + i];
    s4 += src[(size_t)(bx + 4) * 256 + i];
    s5 += src[(size_t)(bx + 5) * 256 + i];
    s6 += src[(size_t)(bx + 6) * 256 + i];
    s7 += src[(size_t)(bx + 7) * 256 + i];
  }
  for (; bx < nbs; ++bx) s0 += src[(size_t)bx * 256 + i];
  float acc = ((s0 + s1) + (s2 + s3)) + ((s4 + s5) + (s6 + s7));
  red[i] = acc;
  sums[((size_t)b * KINST + (i & 63)) * 4 + (i >> 6)] = acc;
  if (i == 0) nu_sh = 0;
  __syncthreads();
  {  // dw-uniformity scan, chunked across the B blocks
    int per = (ndw + B - 1) / B;
    int lo = b * per, hi = min(lo + per, ndw);
    float d0 = dw[0];
    int nu = 0;
    for (int x = lo + i; x < hi; x += blockDim.x) nu |= (dw[x] != d0);
    if (nu) atomicOr(&nu_sh, 1);
  }
  __syncthreads();
  if (i < KINST) {
    float m0s = red[i], m1s = red[64 + i], m2s = red[128 + i], cnt = red[192 + i];
    float inv = cnt > 0.f ? 1.f / cnt : 0.f;
    float m0 = m0s * inv, m1 = m1s * inv, m2 = m2s * inv;
    bool isbg = (pal[i] == 0);
    bool nb = (nb_raw[b] != 0) || (nb_raw[4 * b] != 0);  // robust bool width
    float cf = (!isbg || !nb) ? 1.f : 0.f;
    float sc = (!isbg && cnt > 0.f) ? 10.f / (((float)HW - cnt) * sqrtf(cnt)) : 0.f;
    A_g[b * 65 + i] = make_float4(-2.f * m0, -2.f * m1, -2.f * m2,
                                  m0 * m0 + m1 * m1 + m2 * m2 + 1.f);
    Z_g[b * 65 + i] = make_float4(isbg ? 0.f : m0, isbg ? 0.f : m1,
                                  isbg ? 0.f : m2,
                                  cnt > 0.f ? cf / (3.f * cnt) : 0.f);
    W_g[b * 65 + i] = 300.f * dw[0] * sc;
    scale_sh[i] = sc;
  }
  if (i == KINST) {
    A_g[b * 65 + KINST] = make_float4(0.f, 0.f, 0.f, 1.f);
    Z_g[b * 65 + KINST] = make_float4(0.f, 0.f, 0.f, 0.f);
    W_g[b * 65 + KINST] = 0.f;
  }
  __syncthreads();
  if (i == 0) flagp[b] = nu_sh;
  if (nu_sh) {
    float* ct = cw_g + (size_t)b * KINST * 65;
    for (int t2 = i; t2 < KINST * 65; t2 += blockDim.x) {
      int kk = t2 / 65, j = t2 - kk * 65;
      float v = 0.f;
      if (j < KINST && j != kk) v = 300.f * dw[kk * KINST + j] * scale_sh[kk];
      ct[t2] = v;
    }
  }
}

// ---------------------------------------------------------------------------
// Pass 3 (hot, R7 body): pixel-per-lane, 4 px/thread; LDS uniform-broadcast
// tables; uniform-dw fast path. res_part: [B][gx][2], plain stores.
// ---------------------------------------------------------------------------
template <bool USE_CACHE>
__global__ __launch_bounds__(256) void k_pix(const float* __restrict__ pred,
                                             const float* __restrict__ targ,
                                             const unsigned char* __restrict__ k0c,
                                             const int* __restrict__ pal,
                                             const float4* __restrict__ A_g,
                                             const float* __restrict__ W_g,
                                             const float4* __restrict__ Z_g,
                                             const float* __restrict__ cw_g,
                                             const int* __restrict__ flagp,
                                             float* __restrict__ res_part,
                                             int HW, int B) {
  int b = blockIdx.y;
  __shared__ float4 A_s[KINST + 1];
  __shared__ float4 Z_s[KINST + 1];
  __shared__ float W_s[KINST + 1];
  __shared__ float cwN[KINST][KINST + 1];
  __shared__ int pal_s[KINST];
  __shared__ int nonuni_s;
  __shared__ float rA[4], rB[4];
  int t = threadIdx.x;
  if (t < KINST + 1) {
    A_s[t] = A_g[b * 65 + t];
    Z_s[t] = Z_g[b * 65 + t];
    W_s[t] = W_g[b * 65 + t];
  }
  if (!USE_CACHE && t < KINST) pal_s[t] = pal[t];
  if (t == 0) {
    int f = 0;
    for (int bb = 0; bb < B; ++bb) f |= flagp[bb];
    nonuni_s = f;
  }
  __syncthreads();
  bool nonuni = nonuni_s != 0;
  if (nonuni) {
    const float* cwb = cw_g + (size_t)b * KINST * 65;
    for (int i = t; i < KINST * 65; i += blockDim.x) (&cwN[0][0])[i] = cwb[i];
    __syncthreads();
  }
  const float* pb = pred + (size_t)b * 3 * HW;
  const float* tb = targ + (size_t)b * 3 * HW;
  const float4* pb4 = (const float4*)pb;
  const float4* tb4 = (const float4*)tb;
  int nq = HW >> 2;
  const uchar4* kb4 = USE_CACHE ? (const uchar4*)(k0c + (size_t)b * HW) : nullptr;
  float intra_l = 0.f, inter_l = 0.f;
  for (int q = blockIdx.x * blockDim.x + t; q < nq;
       q += gridDim.x * blockDim.x) {
    float4 P0 = pb4[q], P1 = pb4[q + nq], P2 = pb4[q + 2 * nq];
    int ka, kc, kd, ke;
    if (USE_CACHE) {
      uchar4 kk = kb4[q];
      ka = kk.x; kc = kk.y; kd = kk.z; ke = kk.w;
    } else {
      float4 T0 = tb4[q], T1 = tb4[q + nq], T2 = tb4[q + 2 * nq];
      ka = decode_k0(T0.x, T1.x, T2.x, pal_s);
      kc = decode_k0(T0.y, T1.y, T2.y, pal_s);
      kd = decode_k0(T0.z, T1.z, T2.z, pal_s);
      ke = decode_k0(T0.w, T1.w, T2.w, pal_s);
    }
    float ppa = fmaf(P0.x, P0.x, fmaf(P1.x, P1.x, P2.x * P2.x));
    float ppb = fmaf(P0.y, P0.y, fmaf(P1.y, P1.y, P2.y * P2.y));
    float ppc = fmaf(P0.z, P0.z, fmaf(P1.z, P1.z, P2.z * P2.z));
    float ppd = fmaf(P0.w, P0.w, fmaf(P1.w, P1.w, P2.w * P2.w));
    float aa = 0.f, ab = 0.f, ac = 0.f, ad = 0.f;
    if (!nonuni) {
      #pragma unroll 8
      for (int k = 0; k < KINST; ++k) {
        float4 a = A_s[k];          // uniform addr -> broadcast b128
        float wv = W_s[k];          // uniform addr -> broadcast b32
        float ra = __builtin_amdgcn_rcpf(
            ppa + fmaf(P0.x, a.x, fmaf(P1.x, a.y, fmaf(P2.x, a.z, a.w))));
        float rb = __builtin_amdgcn_rcpf(
            ppb + fmaf(P0.y, a.x, fmaf(P1.y, a.y, fmaf(P2.y, a.z, a.w))));
        float rc = __builtin_amdgcn_rcpf(
            ppc + fmaf(P0.z, a.x, fmaf(P1.z, a.y, fmaf(P2.z, a.z, a.w))));
        float rd = __builtin_amdgcn_rcpf(
            ppd + fmaf(P0.w, a.x, fmaf(P1.w, a.y, fmaf(P2.w, a.z, a.w))));
        aa = fmaf(ra, wv, aa); ab = fmaf(rb, wv, ab);
        ac = fmaf(rc, wv, ac); ad = fmaf(rd, wv, ad);
      }
      // diagonal (k==k0) subtract + invalid-pixel mask (LDS gathers)
      {
        float4 a = A_s[ka]; float wv = W_s[ka];
        float r = __builtin_amdgcn_rcpf(
            ppa + fmaf(P0.x, a.x, fmaf(P1.x, a.y, fmaf(P2.x, a.z, a.w))));
        aa = (ka < KINST) ? aa - wv * r : 0.f;
      }
      {
        float4 a = A_s[kc]; float wv = W_s[kc];
        float r = __builtin_amdgcn_rcpf(
            ppb + fmaf(P0.y, a.x, fmaf(P1.y, a.y, fmaf(P2.y, a.z, a.w))));
        ab = (kc < KINST) ? ab - wv * r : 0.f;
      }
      {
        float4 a = A_s[kd]; float wv = W_s[kd];
        float r = __builtin_amdgcn_rcpf(
            ppc + fmaf(P0.z, a.x, fmaf(P1.z, a.y, fmaf(P2.z, a.z, a.w))));
        ac = (kd < KINST) ? ac - wv * r : 0.f;
      }
      {
        float4 a = A_s[ke]; float wv = W_s[ke];
        float r = __builtin_amdgcn_rcpf(
            ppd + fmaf(P0.w, a.x, fmaf(P1.w, a.y, fmaf(P2.w, a.z, a.w))));
        ad = (ke < KINST) ? ad - wv * r : 0.f;
      }
    } else {
      #pragma unroll 4
      for (int k = 0; k < KINST; ++k) {
        float4 a = A_s[k];
        float ra = __builtin_amdgcn_rcpf(
            ppa + fmaf(P0.x, a.x, fmaf(P1.x, a.y, fmaf(P2.x, a.z, a.w))));
        float rb = __builtin_amdgcn_rcpf(
            ppb + fmaf(P0.y, a.x, fmaf(P1.y, a.y, fmaf(P2.y, a.z, a.w))));
        float rc = __builtin_amdgcn_rcpf(
            ppc + fmaf(P0.z, a.x, fmaf(P1.z, a.y, fmaf(P2.z, a.z, a.w))));
        float rd = __builtin_amdgcn_rcpf(
            ppd + fmaf(P0.w, a.x, fmaf(P1.w, a.y, fmaf(P2.w, a.z, a.w))));
        aa = fmaf(ra, cwN[k][ka], aa); ab = fmaf(rb, cwN[k][kc], ab);
        ac = fmaf(rc, cwN[k][kd], ac); ad = fmaf(rd, cwN[k][ke], ad);
      }
    }
    inter_l += (aa + ab) + (ac + ad);
    // intra: huber toward own bg-zeroed mean; f_intra folds cf/(3*cnt)
    {
      float4 z = Z_s[ka];
      float q0 = fabsf(P0.x - z.x), q1 = fabsf(P1.x - z.y), q2 = fabsf(P2.x - z.z);
      float hp = (q0 < 1.f ? 0.5f * q0 * q0 : q0 - 0.5f) +
                 (q1 < 1.f ? 0.5f * q1 * q1 : q1 - 0.5f) +
                 (q2 < 1.f ? 0.5f * q2 * q2 : q2 - 0.5f);
      intra_l = fmaf(hp, z.w, intra_l);
    }
    {
      float4 z = Z_s[kc];
      float q0 = fabsf(P0.y - z.x), q1 = fabsf(P1.y - z.y), q2 = fabsf(P2.y - z.z);
      float hp = (q0 < 1.f ? 0.5f * q0 * q0 : q0 - 0.5f) +
                 (q1 < 1.f ? 0.5f * q1 * q1 : q1 - 0.5f) +
                 (q2 < 1.f ? 0.5f * q2 * q2 : q2 - 0.5f);
      intra_l = fmaf(hp, z.w, intra_l);
    }
    {
      float4 z = Z_s[kd];
      float q0 = fabsf(P0.z - z.x), q1 = fabsf(P1.z - z.y), q2 = fabsf(P2.z - z.z);
      float hp = (q0 < 1.f ? 0.5f * q0 * q0 : q0 - 0.5f) +
                 (q1 < 1.f ? 0.5f * q1 * q1 : q1 - 0.5f) +
                 (q2 < 1.f ? 0.5f * q2 * q2 : q2 - 0.5f);
      intra_l = fmaf(hp, z.w, intra_l);
    }
    {
      float4 z = Z_s[ke];
      float q0 = fabsf(P0.w - z.x), q1 = fabsf(P1.w - z.y), q2 = fabsf(P2.w - z.z);
      float hp = (q0 < 1.f ? 0.5f * q0 * q0 : q0 - 0.5f) +
                 (q1 < 1.f ? 0.5f * q1 * q1 : q1 - 0.5f) +
                 (q2 < 1.f ? 0.5f * q2 * q2 : q2 - 0.5f);
      intra_l = fmaf(hp, z.w, intra_l);
    }
  }
  // scalar tail pixels (HW % 4 != 0 only)
  for (int i = (nq << 2) + blockIdx.x * blockDim.x + t; i < HW;
       i += gridDim.x * blockDim.x) {
    float p0 = pb[i], p1 = pb[i + HW], p2 = pb[i + 2 * HW];
    int k0 = USE_CACHE ? (int)k0c[(size_t)b * HW + i]
                       : decode_k0(tb[i], tb[i + HW], tb[i + 2 * HW], pal_s);
    float pp = fmaf(p0, p0, fmaf(p1, p1, p2 * p2));
    float acc = 0.f;
    for (int k = 0; k < KINST; ++k) {
      float4 a = A_s[k];
      float r = __builtin_amdgcn_rcpf(
          pp + fmaf(p0, a.x, fmaf(p1, a.y, fmaf(p2, a.z, a.w))));
      float c = nonuni ? cwN[k][k0]
                       : ((k == k0 || k0 >= KINST) ? 0.f : W_s[k]);
      acc = fmaf(r, c, acc);
    }
    inter_l += acc;
    float4 z = Z_s[k0];
    float q0 = fabsf(p0 - z.x), q1 = fabsf(p1 - z.y), q2 = fabsf(p2 - z.z);
    float hp = (q0 < 1.f ? 0.5f * q0 * q0 : q0 - 0.5f) +
               (q1 < 1.f ? 0.5f * q1 * q1 : q1 - 0.5f) +
               (q2 < 1.f ? 0.5f * q2 * q2 : q2 - 0.5f);
    intra_l = fmaf(hp, z.w, intra_l);
  }
  for (int o = 32; o > 0; o >>= 1) {
    intra_l += __shfl_down(intra_l, o, 64);
    inter_l += __shfl_down(inter_l, o, 64);
  }
  int wid = t >> 6;
  if ((t & 63) == 0) { rA[wid] = intra_l; rB[wid] = inter_l; }
  __syncthreads();
  if (t == 0) {
    float a = 0.f, c = 0.f;
    for (int i = 0; i < 4; ++i) { a += rA[i]; c += rB[i]; }
    float* rp = res_part + ((size_t)b * gridDim.x + blockIdx.x) * 2;
    rp[0] = a; rp[1] = c;  // plain store, no atomics
  }
}

// ---------------------------------------------------------------------------
// Pass 4 (grid=B, R6-proven form): per-b pairwise repulsion + combine;
// atomicAdd into zeroed out[0].
// ---------------------------------------------------------------------------
__global__ __launch_bounds__(256) void k_final(const float* __restrict__ sums,
                                               const int* __restrict__ pal,
                                               const unsigned char* __restrict__ nb_raw,
                                               const float* __restrict__ dw,
                                               const float* __restrict__ res_part,
                                               int ngx,
                                               float* __restrict__ out,
                                               int B, int HW) {
  int b = blockIdx.x;
  __shared__ float4 zf[KINST];
  __shared__ float rA[4], rB[4], rC[4], rD[4], rE[4];
  int t = threadIdx.x;
  if (t < KINST) {
    float4 s = ((const float4*)sums)[b * KINST + t];
    float cnt = s.w;
    float inv = cnt > 0.f ? 1.f / cnt : 0.f;
    bool isbg = (pal[t] == 0);
    bool nb = (nb_raw[b] != 0) || (nb_raw[4 * b] != 0);
    float cf = (!isbg || !nb) ? 1.f : 0.f;
    zf[t] = make_float4(isbg ? 0.f : s.x * inv, isbg ? 0.f : s.y * inv,
                        isbg ? 0.f : s.z * inv, cf);
  }
  __syncthreads();
  float psum = 0.f, pcnt = 0.f, cfs = 0.f, ra = 0.f, rc = 0.f;
  for (int idx = t; idx < KINST * KINST; idx += blockDim.x) {
    int j = idx >> 6, k = idx & 63;
    if (j < k) {
      float4 a = zf[j], c4 = zf[k];
      float m = a.w * c4.w;
      float d0 = a.x - c4.x, d1 = a.y - c4.y, d2 = a.z - c4.z;
      float sqd = d0 * d0 + d1 * d1 + d2 * d2;
      psum += dw[j * KINST + k] * 300.f / (sqd + 1.f) * m;
      pcnt += m;
    }
  }
  if (t < KINST) cfs = zf[t].w;
  for (int bx = t; bx < ngx; bx += blockDim.x) {
    const float* rp = res_part + ((size_t)b * ngx + bx) * 2;
    ra += rp[0]; rc += rp[1];
  }
  for (int o = 32; o > 0; o >>= 1) {
    psum += __shfl_down(psum, o, 64);
    pcnt += __shfl_down(pcnt, o, 64);
    cfs += __shfl_down(cfs, o, 64);
    ra += __shfl_down(ra, o, 64);
    rc += __shfl_down(rc, o, 64);
  }
  int wid = t >> 6;
  if ((t & 63) == 0) {
    rA[wid] = psum; rB[wid] = pcnt; rC[wid] = cfs; rD[wid] = ra; rE[wid] = rc;
  }
  __syncthreads();
  if (t == 0) {
    float ps = 0.f, pc = 0.f, cs = 0.f, sa = 0.f, sc2 = 0.f;
    for (int i = 0; i < 4; ++i) {
      ps += rA[i]; pc += rB[i]; cs += rC[i]; sa += rD[i]; sc2 += rE[i];
    }
    float mean_sep = pc > 0.f ? ps / fmaxf(pc, 1.f) : 0.f;
    float ct = fmaxf(cs, 1.f);
    atomicAdd(out, ((sa + sc2 + mean_sep) / ct) / (float)B);
  }
}

extern "C" void kernel_launch(void* const* d_in, const int* in_sizes, int n_in,
                              void* d_out, int out_size, void* d_ws, size_t ws_size,
                              hipStream_t stream) {
  const float* pred = (const float*)d_in[0];
  const float* targ = (const float*)d_in[1];
  const unsigned char* nb = (const unsigned char*)d_in[2];
  const float* dw = (const float*)d_in[3];
  const int* pal = (const int*)d_in[4];
  int B = in_sizes[2];                 // 4
  int ndw = in_sizes[3];               // K*K = 4096
  int HW = in_sizes[0] / (3 * B);      // 262144  (kernels assume K==64)
  const int GX = 256;                  // k_pix blocks per b

  // ws layout (floats): partialS[B*nbs*256] | sums[B*256] | res_part[B*GX*2]
  //                     | flagp[B] | A_g | W_g | Z_g | cw_g ; bytes: k0c[B*HW]
  auto floats_needed = [&](int nbs) -> size_t {
    return (size_t)B * nbs * 256 + (size_t)B * 256 + (size_t)B * GX * 2 + B +
           (size_t)B * 65 * 4 + (size_t)B * 65 + (size_t)B * 65 * 4 +
           (size_t)B * KINST * 65;
  };
  int nbs = 128;
  bool use_cache = true;
  if (ws_size < floats_needed(128) * 4 + (size_t)B * HW) {
    if (ws_size >= floats_needed(32) * 4 + (size_t)B * HW) nbs = 32;
    else { nbs = 32; use_cache = false; }
  }
  float* partialS = (float*)d_ws;
  float* sums = partialS + (size_t)B * nbs * 256;
  float* res_part = sums + (size_t)B * 256;
  int* flagp = (int*)(res_part + (size_t)B * GX * 2);
  float4* A_g = (float4*)(flagp + B);
  float* W_g = (float*)(A_g + (size_t)B * 65);
  float4* Z_g = (float4*)(W_g + (size_t)B * 65);
  float* cw_g = (float*)(Z_g + (size_t)B * 65);
  unsigned char* k0c = use_cache ? (unsigned char*)(cw_g + (size_t)B * KINST * 65)
                                 : nullptr;

  hipMemsetAsync(d_out, 0, sizeof(float), stream);
  k_stats<<<dim3(nbs, B), 256, 0, stream>>>(pred, targ, pal, partialS, k0c, HW);
  k_reduce<<<B, 256, 0, stream>>>(partialS, dw, pal, nb, ndw, nbs, sums, A_g,
                                  W_g, Z_g, cw_g, flagp, B, HW);
  if (use_cache)
    k_pix<true><<<dim3(GX, B), 256, 0, stream>>>(pred, targ, k0c, pal, A_g, W_g,
                                                 Z_g, cw_g, flagp, res_part, HW, B);
  else
    k_pix<false><<<dim3(GX, B), 256, 0, stream>>>(pred, targ, k0c, pal, A_g, W_g,
                                                  Z_g, cw_g, flagp, res_part, HW, B);
  k_final<<<B, 256, 0, stream>>>(sums, pal, nb, dw, res_part, GX,
                                 (float*)d_out, B, HW);
}

// Round 14
// 54.998 us; speedup vs baseline: 4.9269x; 1.0942x over previous
//
#include <hip/hip_runtime.h>

#define KINST 64

typedef float v2f __attribute__((ext_vector_type(2)));

__device__ __forceinline__ int decode_k0(float t0, float t1, float t2,
                                         const int* pal_s) {
  int pid = (int)(fmaf(t0, 65536.f, fmaf(t1, 256.f, t2)) + 0.5f);
  if (pid >= 0 && pid < KINST && pal_s[pid] == pid) return pid;  // fast path
  for (int j = 0; j < KINST; ++j)
    if (pal_s[j] == pid) return j;
  return KINST;  // no palette match
}

// ---------------------------------------------------------------------------
// Pass 1: per-(b,block) PARTIAL histograms via LDS atomics; plain coalesced
// stores. Block (0,0) also zeroes out[0] (replaces the memset dispatch).
// partialS: [B][nbs][256], index i = c*64+k.
// ---------------------------------------------------------------------------
__global__ __launch_bounds__(256) void k_stats(const float* __restrict__ pred,
                                               const float* __restrict__ targ,
                                               const int* __restrict__ pal,
                                               float* __restrict__ partialS,
                                               unsigned char* __restrict__ k0c,
                                               float* __restrict__ out,
                                               int HW) {
  int b = blockIdx.y;
  __shared__ float ls[4][4][KINST];  // [wave][component][k]
  __shared__ int pal_s[KINST];
  if (blockIdx.x == 0 && blockIdx.y == 0 && threadIdx.x == 0) out[0] = 0.f;
  for (int i = threadIdx.x; i < 4 * 4 * KINST; i += blockDim.x)
    (&ls[0][0][0])[i] = 0.f;
  for (int i = threadIdx.x; i < KINST; i += blockDim.x) pal_s[i] = pal[i];
  __syncthreads();
  int w = threadIdx.x >> 6;
  const float* tb = targ + (size_t)b * 3 * HW;
  const float* pb = pred + (size_t)b * 3 * HW;
  unsigned char* kb = k0c ? k0c + (size_t)b * HW : nullptr;
  int nq = HW >> 2;
  const float4* tb4 = (const float4*)tb;
  const float4* pb4 = (const float4*)pb;
  for (int q = blockIdx.x * blockDim.x + threadIdx.x; q < nq;
       q += gridDim.x * blockDim.x) {
    float4 t0 = tb4[q], t1 = tb4[q + nq], t2 = tb4[q + 2 * nq];
    float4 p0 = pb4[q], p1 = pb4[q + nq], p2 = pb4[q + 2 * nq];
    int ka = decode_k0(t0.x, t1.x, t2.x, pal_s);
    int kc = decode_k0(t0.y, t1.y, t2.y, pal_s);
    int kd = decode_k0(t0.z, t1.z, t2.z, pal_s);
    int ke = decode_k0(t0.w, t1.w, t2.w, pal_s);
    if (ka < KINST) {
      atomicAdd(&ls[w][0][ka], p0.x); atomicAdd(&ls[w][1][ka], p1.x);
      atomicAdd(&ls[w][2][ka], p2.x); atomicAdd(&ls[w][3][ka], 1.f);
    }
    if (kc < KINST) {
      atomicAdd(&ls[w][0][kc], p0.y); atomicAdd(&ls[w][1][kc], p1.y);
      atomicAdd(&ls[w][2][kc], p2.y); atomicAdd(&ls[w][3][kc], 1.f);
    }
    if (kd < KINST) {
      atomicAdd(&ls[w][0][kd], p0.z); atomicAdd(&ls[w][1][kd], p1.z);
      atomicAdd(&ls[w][2][kd], p2.z); atomicAdd(&ls[w][3][kd], 1.f);
    }
    if (ke < KINST) {
      atomicAdd(&ls[w][0][ke], p0.w); atomicAdd(&ls[w][1][ke], p1.w);
      atomicAdd(&ls[w][2][ke], p2.w); atomicAdd(&ls[w][3][ke], 1.f);
    }
    if (kb) {
      uchar4 kk = make_uchar4((unsigned char)ka, (unsigned char)kc,
                              (unsigned char)kd, (unsigned char)ke);
      *(uchar4*)(kb + 4 * (size_t)q) = kk;
    }
  }
  // scalar tail (HW % 4 != 0 only)
  for (int i = (nq << 2) + blockIdx.x * blockDim.x + threadIdx.x; i < HW;
       i += gridDim.x * blockDim.x) {
    int k0 = decode_k0(tb[i], tb[i + HW], tb[i + 2 * HW], pal_s);
    if (kb) kb[i] = (unsigned char)k0;
    if (k0 < KINST) {
      atomicAdd(&ls[w][0][k0], pb[i]); atomicAdd(&ls[w][1][k0], pb[i + HW]);
      atomicAdd(&ls[w][2][k0], pb[i + 2 * HW]); atomicAdd(&ls[w][3][k0], 1.f);
    }
  }
  __syncthreads();
  float* o = partialS + ((size_t)b * gridDim.x + blockIdx.x) * 256;
  int i = threadIdx.x;  // i = c*64+k
  int c = i >> 6, k = i & 63;
  o[i] = ls[0][c][k] + ls[1][c][k] + ls[2][c][k] + ls[3][c][k];
}

// ---------------------------------------------------------------------------
// Pass 2 (grid=B): reduce partials (unroll 8) -> sums + per-(b,k) tables.
// ---------------------------------------------------------------------------
__global__ __launch_bounds__(256) void k_reduce(const float* __restrict__ partialS,
                                                const float* __restrict__ dw,
                                                const int* __restrict__ pal,
                                                const unsigned char* __restrict__ nb_raw,
                                                int ndw, int nbs,
                                                float* __restrict__ sums,
                                                float4* __restrict__ A_g,
                                                float* __restrict__ W_g,
                                                float4* __restrict__ Z_g,
                                                float* __restrict__ cw_g,
                                                int* __restrict__ flagp,
                                                int B, int HW) {
  int b = blockIdx.x;
  int i = threadIdx.x;
  __shared__ float red[256];
  __shared__ float scale_sh[KINST];
  __shared__ int nu_sh;
  const float* src = partialS + (size_t)b * nbs * 256;
  float s0 = 0.f, s1 = 0.f, s2 = 0.f, s3 = 0.f;
  float s4 = 0.f, s5 = 0.f, s6 = 0.f, s7 = 0.f;
  int bx = 0;
  for (; bx + 8 <= nbs; bx += 8) {
    s0 += src[(size_t)(bx + 0) * 256 + i];
    s1 += src[(size_t)(bx + 1) * 256 + i];
    s2 += src[(size_t)(bx + 2) * 256 + i];
    s3 += src[(size_t)(bx + 3) * 256 + i];
    s4 += src[(size_t)(bx + 4) * 256 + i];
    s5 += src[(size_t)(bx + 5) * 256 + i];
    s6 += src[(size_t)(bx + 6) * 256 + i];
    s7 += src[(size_t)(bx + 7) * 256 + i];
  }
  for (; bx < nbs; ++bx) s0 += src[(size_t)bx * 256 + i];
  float acc = ((s0 + s1) + (s2 + s3)) + ((s4 + s5) + (s6 + s7));
  red[i] = acc;
  sums[((size_t)b * KINST + (i & 63)) * 4 + (i >> 6)] = acc;
  if (i == 0) nu_sh = 0;
  __syncthreads();
  {  // dw-uniformity scan, chunked across the B blocks
    int per = (ndw + B - 1) / B;
    int lo = b * per, hi = min(lo + per, ndw);
    float d0 = dw[0];
    int nu = 0;
    for (int x = lo + i; x < hi; x += blockDim.x) nu |= (dw[x] != d0);
    if (nu) atomicOr(&nu_sh, 1);
  }
  __syncthreads();
  if (i < KINST) {
    float m0s = red[i], m1s = red[64 + i], m2s = red[128 + i], cnt = red[192 + i];
    float inv = cnt > 0.f ? 1.f / cnt : 0.f;
    float m0 = m0s * inv, m1 = m1s * inv, m2 = m2s * inv;
    bool isbg = (pal[i] == 0);
    bool nb = (nb_raw[b] != 0) || (nb_raw[4 * b] != 0);  // robust bool width
    float cf = (!isbg || !nb) ? 1.f : 0.f;
    float sc = (!isbg && cnt > 0.f) ? 10.f / (((float)HW - cnt) * sqrtf(cnt)) : 0.f;
    A_g[b * 65 + i] = make_float4(-2.f * m0, -2.f * m1, -2.f * m2,
                                  m0 * m0 + m1 * m1 + m2 * m2 + 1.f);
    Z_g[b * 65 + i] = make_float4(isbg ? 0.f : m0, isbg ? 0.f : m1,
                                  isbg ? 0.f : m2,
                                  cnt > 0.f ? cf / (3.f * cnt) : 0.f);
    W_g[b * 65 + i] = 300.f * dw[0] * sc;
    scale_sh[i] = sc;
  }
  if (i == KINST) {
    A_g[b * 65 + KINST] = make_float4(0.f, 0.f, 0.f, 1.f);
    Z_g[b * 65 + KINST] = make_float4(0.f, 0.f, 0.f, 0.f);
    W_g[b * 65 + KINST] = 0.f;
  }
  __syncthreads();
  if (i == 0) flagp[b] = nu_sh;
  if (nu_sh) {
    float* ct = cw_g + (size_t)b * KINST * 65;
    for (int t2 = i; t2 < KINST * 65; t2 += blockDim.x) {
      int kk = t2 / 65, j = t2 - kk * 65;
      float v = 0.f;
      if (j < KINST && j != kk) v = 300.f * dw[kk * KINST + j] * scale_sh[kk];
      ct[t2] = v;
    }
  }
}

// ---------------------------------------------------------------------------
// Pass 3 (hot): pixel-per-lane, 4 px/thread; LDS uniform-broadcast tables.
// Inner loop restructured as 2x float2 packed chains to invite v_pk_fma_f32
// (gfx950 dual-pumped f32). rcp stays scalar (no packed transcendental).
// ---------------------------------------------------------------------------
template <bool USE_CACHE>
__global__ __launch_bounds__(256) void k_pix(const float* __restrict__ pred,
                                             const float* __restrict__ targ,
                                             const unsigned char* __restrict__ k0c,
                                             const int* __restrict__ pal,
                                             const float4* __restrict__ A_g,
                                             const float* __restrict__ W_g,
                                             const float4* __restrict__ Z_g,
                                             const float* __restrict__ cw_g,
                                             const int* __restrict__ flagp,
                                             float* __restrict__ res_part,
                                             int HW, int B) {
  int b = blockIdx.y;
  __shared__ float4 A_s[KINST + 1];
  __shared__ float4 Z_s[KINST + 1];
  __shared__ float W_s[KINST + 1];
  __shared__ float cwN[KINST][KINST + 1];
  __shared__ int pal_s[KINST];
  __shared__ int nonuni_s;
  __shared__ float rA[4], rB[4];
  int t = threadIdx.x;
  if (t < KINST + 1) {
    A_s[t] = A_g[b * 65 + t];
    Z_s[t] = Z_g[b * 65 + t];
    W_s[t] = W_g[b * 65 + t];
  }
  if (!USE_CACHE && t < KINST) pal_s[t] = pal[t];
  if (t == 0) {
    int f = 0;
    for (int bb = 0; bb < B; ++bb) f |= flagp[bb];
    nonuni_s = f;
  }
  __syncthreads();
  bool nonuni = nonuni_s != 0;
  if (nonuni) {
    const float* cwb = cw_g + (size_t)b * KINST * 65;
    for (int i = t; i < KINST * 65; i += blockDim.x) (&cwN[0][0])[i] = cwb[i];
    __syncthreads();
  }
  const float* pb = pred + (size_t)b * 3 * HW;
  const float* tb = targ + (size_t)b * 3 * HW;
  const float4* pb4 = (const float4*)pb;
  const float4* tb4 = (const float4*)tb;
  int nq = HW >> 2;
  const uchar4* kb4 = USE_CACHE ? (const uchar4*)(k0c + (size_t)b * HW) : nullptr;
  float intra_l = 0.f, inter_l = 0.f;
  for (int q = blockIdx.x * blockDim.x + t; q < nq;
       q += gridDim.x * blockDim.x) {
    float4 P0 = pb4[q], P1 = pb4[q + nq], P2 = pb4[q + 2 * nq];
    int ka, kc, kd, ke;
    if (USE_CACHE) {
      uchar4 kk = kb4[q];
      ka = kk.x; kc = kk.y; kd = kk.z; ke = kk.w;
    } else {
      float4 T0 = tb4[q], T1 = tb4[q + nq], T2 = tb4[q + 2 * nq];
      ka = decode_k0(T0.x, T1.x, T2.x, pal_s);
      kc = decode_k0(T0.y, T1.y, T2.y, pal_s);
      kd = decode_k0(T0.z, T1.z, T2.z, pal_s);
      ke = decode_k0(T0.w, T1.w, T2.w, pal_s);
    }
    float ppa = fmaf(P0.x, P0.x, fmaf(P1.x, P1.x, P2.x * P2.x));
    float ppb = fmaf(P0.y, P0.y, fmaf(P1.y, P1.y, P2.y * P2.y));
    float ppc = fmaf(P0.z, P0.z, fmaf(P1.z, P1.z, P2.z * P2.z));
    float ppd = fmaf(P0.w, P0.w, fmaf(P1.w, P1.w, P2.w * P2.w));
    float aa = 0.f, ab = 0.f, ac = 0.f, ad = 0.f;
    if (!nonuni) {
      // packed: pixels (x,y) in pair 01, (z,w) in pair 23
      v2f pp01 = {ppa, ppb}, pp23 = {ppc, ppd};
      v2f P0a = {P0.x, P0.y}, P0b = {P0.z, P0.w};
      v2f P1a = {P1.x, P1.y}, P1b = {P1.z, P1.w};
      v2f P2a = {P2.x, P2.y}, P2b = {P2.z, P2.w};
      v2f acc01 = {0.f, 0.f}, acc23 = {0.f, 0.f};
      #pragma unroll 8
      for (int k = 0; k < KINST; ++k) {
        float4 a = A_s[k];          // uniform addr -> broadcast b128
        float wv = W_s[k];          // uniform addr -> broadcast b32
        v2f ax = {a.x, a.x}, ay = {a.y, a.y}, az = {a.z, a.z}, aw = {a.w, a.w};
        v2f wv2 = {wv, wv};
        v2f t01 = __builtin_elementwise_fma(P0a, ax, aw);
        t01 = __builtin_elementwise_fma(P1a, ay, t01);
        t01 = __builtin_elementwise_fma(P2a, az, t01);
        v2f arg01 = pp01 + t01;
        v2f t23 = __builtin_elementwise_fma(P0b, ax, aw);
        t23 = __builtin_elementwise_fma(P1b, ay, t23);
        t23 = __builtin_elementwise_fma(P2b, az, t23);
        v2f arg23 = pp23 + t23;
        v2f r01 = {__builtin_amdgcn_rcpf(arg01.x), __builtin_amdgcn_rcpf(arg01.y)};
        v2f r23 = {__builtin_amdgcn_rcpf(arg23.x), __builtin_amdgcn_rcpf(arg23.y)};
        acc01 = __builtin_elementwise_fma(r01, wv2, acc01);
        acc23 = __builtin_elementwise_fma(r23, wv2, acc23);
      }
      aa = acc01.x; ab = acc01.y; ac = acc23.x; ad = acc23.y;
      // diagonal (k==k0) subtract + invalid-pixel mask (LDS gathers)
      {
        float4 a = A_s[ka]; float wv = W_s[ka];
        float r = __builtin_amdgcn_rcpf(
            ppa + fmaf(P0.x, a.x, fmaf(P1.x, a.y, fmaf(P2.x, a.z, a.w))));
        aa = (ka < KINST) ? aa - wv * r : 0.f;
      }
      {
        float4 a = A_s[kc]; float wv = W_s[kc];
        float r = __builtin_amdgcn_rcpf(
            ppb + fmaf(P0.y, a.x, fmaf(P1.y, a.y, fmaf(P2.y, a.z, a.w))));
        ab = (kc < KINST) ? ab - wv * r : 0.f;
      }
      {
        float4 a = A_s[kd]; float wv = W_s[kd];
        float r = __builtin_amdgcn_rcpf(
            ppc + fmaf(P0.z, a.x, fmaf(P1.z, a.y, fmaf(P2.z, a.z, a.w))));
        ac = (kd < KINST) ? ac - wv * r : 0.f;
      }
      {
        float4 a = A_s[ke]; float wv = W_s[ke];
        float r = __builtin_amdgcn_rcpf(
            ppd + fmaf(P0.w, a.x, fmaf(P1.w, a.y, fmaf(P2.w, a.z, a.w))));
        ad = (ke < KINST) ? ad - wv * r : 0.f;
      }
    } else {
      #pragma unroll 4
      for (int k = 0; k < KINST; ++k) {
        float4 a = A_s[k];
        float ra = __builtin_amdgcn_rcpf(
            ppa + fmaf(P0.x, a.x, fmaf(P1.x, a.y, fmaf(P2.x, a.z, a.w))));
        float rb = __builtin_amdgcn_rcpf(
            ppb + fmaf(P0.y, a.x, fmaf(P1.y, a.y, fmaf(P2.y, a.z, a.w))));
        float rc = __builtin_amdgcn_rcpf(
            ppc + fmaf(P0.z, a.x, fmaf(P1.z, a.y, fmaf(P2.z, a.z, a.w))));
        float rd = __builtin_amdgcn_rcpf(
            ppd + fmaf(P0.w, a.x, fmaf(P1.w, a.y, fmaf(P2.w, a.z, a.w))));
        aa = fmaf(ra, cwN[k][ka], aa); ab = fmaf(rb, cwN[k][kc], ab);
        ac = fmaf(rc, cwN[k][kd], ac); ad = fmaf(rd, cwN[k][ke], ad);
      }
    }
    inter_l += (aa + ab) + (ac + ad);
    // intra: huber toward own bg-zeroed mean; f_intra folds cf/(3*cnt)
    {
      float4 z = Z_s[ka];
      float q0 = fabsf(P0.x - z.x), q1 = fabsf(P1.x - z.y), q2 = fabsf(P2.x - z.z);
      float hp = (q0 < 1.f ? 0.5f * q0 * q0 : q0 - 0.5f) +
                 (q1 < 1.f ? 0.5f * q1 * q1 : q1 - 0.5f) +
                 (q2 < 1.f ? 0.5f * q2 * q2 : q2 - 0.5f);
      intra_l = fmaf(hp, z.w, intra_l);
    }
    {
      float4 z = Z_s[kc];
      float q0 = fabsf(P0.y - z.x), q1 = fabsf(P1.y - z.y), q2 = fabsf(P2.y - z.z);
      float hp = (q0 < 1.f ? 0.5f * q0 * q0 : q0 - 0.5f) +
                 (q1 < 1.f ? 0.5f * q1 * q1 : q1 - 0.5f) +
                 (q2 < 1.f ? 0.5f * q2 * q2 : q2 - 0.5f);
      intra_l = fmaf(hp, z.w, intra_l);
    }
    {
      float4 z = Z_s[kd];
      float q0 = fabsf(P0.z - z.x), q1 = fabsf(P1.z - z.y), q2 = fabsf(P2.z - z.z);
      float hp = (q0 < 1.f ? 0.5f * q0 * q0 : q0 - 0.5f) +
                 (q1 < 1.f ? 0.5f * q1 * q1 : q1 - 0.5f) +
                 (q2 < 1.f ? 0.5f * q2 * q2 : q2 - 0.5f);
      intra_l = fmaf(hp, z.w, intra_l);
    }
    {
      float4 z = Z_s[ke];
      float q0 = fabsf(P0.w - z.x), q1 = fabsf(P1.w - z.y), q2 = fabsf(P2.w - z.z);
      float hp = (q0 < 1.f ? 0.5f * q0 * q0 : q0 - 0.5f) +
                 (q1 < 1.f ? 0.5f * q1 * q1 : q1 - 0.5f) +
                 (q2 < 1.f ? 0.5f * q2 * q2 : q2 - 0.5f);
      intra_l = fmaf(hp, z.w, intra_l);
    }
  }
  // scalar tail pixels (HW % 4 != 0 only)
  for (int i = (nq << 2) + blockIdx.x * blockDim.x + t; i < HW;
       i += gridDim.x * blockDim.x) {
    float p0 = pb[i], p1 = pb[i + HW], p2 = pb[i + 2 * HW];
    int k0 = USE_CACHE ? (int)k0c[(size_t)b * HW + i]
                       : decode_k0(tb[i], tb[i + HW], tb[i + 2 * HW], pal_s);
    float pp = fmaf(p0, p0, fmaf(p1, p1, p2 * p2));
    float acc = 0.f;
    for (int k = 0; k < KINST; ++k) {
      float4 a = A_s[k];
      float r = __builtin_amdgcn_rcpf(
          pp + fmaf(p0, a.x, fmaf(p1, a.y, fmaf(p2, a.z, a.w))));
      float c = nonuni ? cwN[k][k0]
                       : ((k == k0 || k0 >= KINST) ? 0.f : W_s[k]);
      acc = fmaf(r, c, acc);
    }
    inter_l += acc;
    float4 z = Z_s[k0];
    float q0 = fabsf(p0 - z.x), q1 = fabsf(p1 - z.y), q2 = fabsf(p2 - z.z);
    float hp = (q0 < 1.f ? 0.5f * q0 * q0 : q0 - 0.5f) +
               (q1 < 1.f ? 0.5f * q1 * q1 : q1 - 0.5f) +
               (q2 < 1.f ? 0.5f * q2 * q2 : q2 - 0.5f);
    intra_l = fmaf(hp, z.w, intra_l);
  }
  for (int o = 32; o > 0; o >>= 1) {
    intra_l += __shfl_down(intra_l, o, 64);
    inter_l += __shfl_down(inter_l, o, 64);
  }
  int wid = t >> 6;
  if ((t & 63) == 0) { rA[wid] = intra_l; rB[wid] = inter_l; }
  __syncthreads();
  if (t == 0) {
    float a = 0.f, c = 0.f;
    for (int i = 0; i < 4; ++i) { a += rA[i]; c += rB[i]; }
    float* rp = res_part + ((size_t)b * gridDim.x + blockIdx.x) * 2;
    rp[0] = a; rp[1] = c;  // plain store, no atomics
  }
}

// ---------------------------------------------------------------------------
// Pass 4 (grid=B): per-b pairwise repulsion + combine; atomicAdd into out[0]
// (zeroed by k_stats).
// ---------------------------------------------------------------------------
__global__ __launch_bounds__(256) void k_final(const float* __restrict__ sums,
                                               const int* __restrict__ pal,
                                               const unsigned char* __restrict__ nb_raw,
                                               const float* __restrict__ dw,
                                               const float* __restrict__ res_part,
                                               int ngx,
                                               float* __restrict__ out,
                                               int B, int HW) {
  int b = blockIdx.x;
  __shared__ float4 zf[KINST];
  __shared__ float rA[4], rB[4], rC[4], rD[4], rE[4];
  int t = threadIdx.x;
  if (t < KINST) {
    float4 s = ((const float4*)sums)[b * KINST + t];
    float cnt = s.w;
    float inv = cnt > 0.f ? 1.f / cnt : 0.f;
    bool isbg = (pal[t] == 0);
    bool nb = (nb_raw[b] != 0) || (nb_raw[4 * b] != 0);
    float cf = (!isbg || !nb) ? 1.f : 0.f;
    zf[t] = make_float4(isbg ? 0.f : s.x * inv, isbg ? 0.f : s.y * inv,
                        isbg ? 0.f : s.z * inv, cf);
  }
  __syncthreads();
  float psum = 0.f, pcnt = 0.f, cfs = 0.f, ra = 0.f, rc = 0.f;
  for (int idx = t; idx < KINST * KINST; idx += blockDim.x) {
    int j = idx >> 6, k = idx & 63;
    if (j < k) {
      float4 a = zf[j], c4 = zf[k];
      float m = a.w * c4.w;
      float d0 = a.x - c4.x, d1 = a.y - c4.y, d2 = a.z - c4.z;
      float sqd = d0 * d0 + d1 * d1 + d2 * d2;
      psum += dw[j * KINST + k] * 300.f / (sqd + 1.f) * m;
      pcnt += m;
    }
  }
  if (t < KINST) cfs = zf[t].w;
  for (int bx = t; bx < ngx; bx += blockDim.x) {
    const float* rp = res_part + ((size_t)b * ngx + bx) * 2;
    ra += rp[0]; rc += rp[1];
  }
  for (int o = 32; o > 0; o >>= 1) {
    psum += __shfl_down(psum, o, 64);
    pcnt += __shfl_down(pcnt, o, 64);
    cfs += __shfl_down(cfs, o, 64);
    ra += __shfl_down(ra, o, 64);
    rc += __shfl_down(rc, o, 64);
  }
  int wid = t >> 6;
  if ((t & 63) == 0) {
    rA[wid] = psum; rB[wid] = pcnt; rC[wid] = cfs; rD[wid] = ra; rE[wid] = rc;
  }
  __syncthreads();
  if (t == 0) {
    float ps = 0.f, pc = 0.f, cs = 0.f, sa = 0.f, sc2 = 0.f;
    for (int i = 0; i < 4; ++i) {
      ps += rA[i]; pc += rB[i]; cs += rC[i]; sa += rD[i]; sc2 += rE[i];
    }
    float mean_sep = pc > 0.f ? ps / fmaxf(pc, 1.f) : 0.f;
    float ct = fmaxf(cs, 1.f);
    atomicAdd(out, ((sa + sc2 + mean_sep) / ct) / (float)B);
  }
}

extern "C" void kernel_launch(void* const* d_in, const int* in_sizes, int n_in,
                              void* d_out, int out_size, void* d_ws, size_t ws_size,
                              hipStream_t stream) {
  const float* pred = (const float*)d_in[0];
  const float* targ = (const float*)d_in[1];
  const unsigned char* nb = (const unsigned char*)d_in[2];
  const float* dw = (const float*)d_in[3];
  const int* pal = (const int*)d_in[4];
  int B = in_sizes[2];                 // 4
  int ndw = in_sizes[3];               // K*K = 4096
  int HW = in_sizes[0] / (3 * B);      // 262144  (kernels assume K==64)
  const int GX = 256;                  // k_pix blocks per b

  // ws layout (floats): partialS[B*nbs*256] | sums[B*256] | res_part[B*GX*2]
  //                     | flagp[B] | A_g | W_g | Z_g | cw_g ; bytes: k0c[B*HW]
  auto floats_needed = [&](int nbs) -> size_t {
    return (size_t)B * nbs * 256 + (size_t)B * 256 + (size_t)B * GX * 2 + B +
           (size_t)B * 65 * 4 + (size_t)B * 65 + (size_t)B * 65 * 4 +
           (size_t)B * KINST * 65;
  };
  int nbs = 128;
  bool use_cache = true;
  if (ws_size < floats_needed(128) * 4 + (size_t)B * HW) {
    if (ws_size >= floats_needed(32) * 4 + (size_t)B * HW) nbs = 32;
    else { nbs = 32; use_cache = false; }
  }
  float* partialS = (float*)d_ws;
  float* sums = partialS + (size_t)B * nbs * 256;
  float* res_part = sums + (size_t)B * 256;
  int* flagp = (int*)(res_part + (size_t)B * GX * 2);
  float4* A_g = (float4*)(flagp + B);
  float* W_g = (float*)(A_g + (size_t)B * 65);
  float4* Z_g = (float4*)(W_g + (size_t)B * 65);
  float* cw_g = (float*)(Z_g + (size_t)B * 65);
  unsigned char* k0c = use_cache ? (unsigned char*)(cw_g + (size_t)B * KINST * 65)
                                 : nullptr;

  k_stats<<<dim3(nbs, B), 256, 0, stream>>>(pred, targ, pal, partialS, k0c,
                                            (float*)d_out, HW);
  k_reduce<<<B, 256, 0, stream>>>(partialS, dw, pal, nb, ndw, nbs, sums, A_g,
                                  W_g, Z_g, cw_g, flagp, B, HW);
  if (use_cache)
    k_pix<true><<<dim3(GX, B), 256, 0, stream>>>(pred, targ, k0c, pal, A_g, W_g,
                                                 Z_g, cw_g, flagp, res_part, HW, B);
  else
    k_pix<false><<<dim3(GX, B), 256, 0, stream>>>(pred, targ, k0c, pal, A_g, W_g,
                                                  Z_g, cw_g, flagp, res_part, HW, B);
  k_final<<<B, 256, 0, stream>>>(sums, pal, nb, dw, res_part, GX,
                                 (float*)d_out, B, HW);
}

// Round 15
// 52.632 us; speedup vs baseline: 5.1484x; 1.0450x over previous
//
#include <hip/hip_runtime.h>

#define KINST 64

typedef float v2f __attribute__((ext_vector_type(2)));

__device__ __forceinline__ int decode_k0(float t0, float t1, float t2,
                                         const int* pal_s) {
  int pid = (int)(fmaf(t0, 65536.f, fmaf(t1, 256.f, t2)) + 0.5f);
  if (pid >= 0 && pid < KINST && pal_s[pid] == pid) return pid;  // fast path
  for (int j = 0; j < KINST; ++j)
    if (pal_s[j] == pid) return j;
  return KINST;  // no palette match
}

// ---------------------------------------------------------------------------
// Pass 1: per-(b,block) PARTIAL histograms via LDS atomics; plain coalesced
// stores. Block (0,0) zeroes out[0]. partialS: [B][nbs][256], i = c*64+k.
// ---------------------------------------------------------------------------
__global__ __launch_bounds__(256) void k_stats(const float* __restrict__ pred,
                                               const float* __restrict__ targ,
                                               const int* __restrict__ pal,
                                               float* __restrict__ partialS,
                                               unsigned char* __restrict__ k0c,
                                               float* __restrict__ out,
                                               int HW) {
  int b = blockIdx.y;
  __shared__ float ls[4][4][KINST];  // [wave][component][k]
  __shared__ int pal_s[KINST];
  if (blockIdx.x == 0 && blockIdx.y == 0 && threadIdx.x == 0) out[0] = 0.f;
  for (int i = threadIdx.x; i < 4 * 4 * KINST; i += blockDim.x)
    (&ls[0][0][0])[i] = 0.f;
  for (int i = threadIdx.x; i < KINST; i += blockDim.x) pal_s[i] = pal[i];
  __syncthreads();
  int w = threadIdx.x >> 6;
  const float* tb = targ + (size_t)b * 3 * HW;
  const float* pb = pred + (size_t)b * 3 * HW;
  unsigned char* kb = k0c ? k0c + (size_t)b * HW : nullptr;
  int nq = HW >> 2;
  const float4* tb4 = (const float4*)tb;
  const float4* pb4 = (const float4*)pb;
  for (int q = blockIdx.x * blockDim.x + threadIdx.x; q < nq;
       q += gridDim.x * blockDim.x) {
    float4 t0 = tb4[q], t1 = tb4[q + nq], t2 = tb4[q + 2 * nq];
    float4 p0 = pb4[q], p1 = pb4[q + nq], p2 = pb4[q + 2 * nq];
    int ka = decode_k0(t0.x, t1.x, t2.x, pal_s);
    int kc = decode_k0(t0.y, t1.y, t2.y, pal_s);
    int kd = decode_k0(t0.z, t1.z, t2.z, pal_s);
    int ke = decode_k0(t0.w, t1.w, t2.w, pal_s);
    if (ka < KINST) {
      atomicAdd(&ls[w][0][ka], p0.x); atomicAdd(&ls[w][1][ka], p1.x);
      atomicAdd(&ls[w][2][ka], p2.x); atomicAdd(&ls[w][3][ka], 1.f);
    }
    if (kc < KINST) {
      atomicAdd(&ls[w][0][kc], p0.y); atomicAdd(&ls[w][1][kc], p1.y);
      atomicAdd(&ls[w][2][kc], p2.y); atomicAdd(&ls[w][3][kc], 1.f);
    }
    if (kd < KINST) {
      atomicAdd(&ls[w][0][kd], p0.z); atomicAdd(&ls[w][1][kd], p1.z);
      atomicAdd(&ls[w][2][kd], p2.z); atomicAdd(&ls[w][3][kd], 1.f);
    }
    if (ke < KINST) {
      atomicAdd(&ls[w][0][ke], p0.w); atomicAdd(&ls[w][1][ke], p1.w);
      atomicAdd(&ls[w][2][ke], p2.w); atomicAdd(&ls[w][3][ke], 1.f);
    }
    if (kb) {
      uchar4 kk = make_uchar4((unsigned char)ka, (unsigned char)kc,
                              (unsigned char)kd, (unsigned char)ke);
      *(uchar4*)(kb + 4 * (size_t)q) = kk;
    }
  }
  // scalar tail (HW % 4 != 0 only)
  for (int i = (nq << 2) + blockIdx.x * blockDim.x + threadIdx.x; i < HW;
       i += gridDim.x * blockDim.x) {
    int k0 = decode_k0(tb[i], tb[i + HW], tb[i + 2 * HW], pal_s);
    if (kb) kb[i] = (unsigned char)k0;
    if (k0 < KINST) {
      atomicAdd(&ls[w][0][k0], pb[i]); atomicAdd(&ls[w][1][k0], pb[i + HW]);
      atomicAdd(&ls[w][2][k0], pb[i + 2 * HW]); atomicAdd(&ls[w][3][k0], 1.f);
    }
  }
  __syncthreads();
  float* o = partialS + ((size_t)b * gridDim.x + blockIdx.x) * 256;
  int i = threadIdx.x;  // i = c*64+k
  int c = i >> 6, k = i & 63;
  o[i] = ls[0][c][k] + ls[1][c][k] + ls[2][c][k] + ls[3][c][k];
}

// ---------------------------------------------------------------------------
// Pass 2 (grid=B): reduce partials (unroll 8) -> sums + per-(b,k) tables
// + the K^2 pairwise mean-repulsion (moved from k_final; identical fixed
// iteration order). msep_g[b] = {mean_sep, ct}.
// ---------------------------------------------------------------------------
__global__ __launch_bounds__(256) void k_reduce(const float* __restrict__ partialS,
                                                const float* __restrict__ dw,
                                                const int* __restrict__ pal,
                                                const unsigned char* __restrict__ nb_raw,
                                                int ndw, int nbs,
                                                float4* __restrict__ A_g,
                                                float* __restrict__ W_g,
                                                float4* __restrict__ Z_g,
                                                float* __restrict__ cw_g,
                                                int* __restrict__ flagp,
                                                float2* __restrict__ msep_g,
                                                int B, int HW) {
  int b = blockIdx.x;
  int i = threadIdx.x;
  __shared__ float red[256];
  __shared__ float scale_sh[KINST];
  __shared__ float4 zf[KINST];  // {mz0,mz1,mz2, cf}
  __shared__ float rA[4], rB[4], rC[4];
  __shared__ int nu_sh;
  const float* src = partialS + (size_t)b * nbs * 256;
  float s0 = 0.f, s1 = 0.f, s2 = 0.f, s3 = 0.f;
  float s4 = 0.f, s5 = 0.f, s6 = 0.f, s7 = 0.f;
  int bx = 0;
  for (; bx + 8 <= nbs; bx += 8) {
    s0 += src[(size_t)(bx + 0) * 256 + i];
    s1 += src[(size_t)(bx + 1) * 256 + i];
    s2 += src[(size_t)(bx + 2) * 256 + i];
    s3 += src[(size_t)(bx + 3) * 256 + i];
    s4 += src[(size_t)(bx + 4) * 256 + i];
    s5 += src[(size_t)(bx + 5) * 256 + i];
    s6 += src[(size_t)(bx + 6) * 256 + i];
    s7 += src[(size_t)(bx + 7) * 256 + i];
  }
  for (; bx < nbs; ++bx) s0 += src[(size_t)bx * 256 + i];
  float acc = ((s0 + s1) + (s2 + s3)) + ((s4 + s5) + (s6 + s7));
  red[i] = acc;
  if (i == 0) nu_sh = 0;
  __syncthreads();
  {  // dw-uniformity scan, chunked across the B blocks
    int per = (ndw + B - 1) / B;
    int lo = b * per, hi = min(lo + per, ndw);
    float d0 = dw[0];
    int nu = 0;
    for (int x = lo + i; x < hi; x += blockDim.x) nu |= (dw[x] != d0);
    if (nu) atomicOr(&nu_sh, 1);
  }
  __syncthreads();
  if (i < KINST) {
    float m0s = red[i], m1s = red[64 + i], m2s = red[128 + i], cnt = red[192 + i];
    float inv = cnt > 0.f ? 1.f / cnt : 0.f;
    float m0 = m0s * inv, m1 = m1s * inv, m2 = m2s * inv;
    bool isbg = (pal[i] == 0);
    bool nb = (nb_raw[b] != 0) || (nb_raw[4 * b] != 0);  // robust bool width
    float cf = (!isbg || !nb) ? 1.f : 0.f;
    float sc = (!isbg && cnt > 0.f) ? 10.f / (((float)HW - cnt) * sqrtf(cnt)) : 0.f;
    A_g[b * 65 + i] = make_float4(-2.f * m0, -2.f * m1, -2.f * m2,
                                  m0 * m0 + m1 * m1 + m2 * m2 + 1.f);
    Z_g[b * 65 + i] = make_float4(isbg ? 0.f : m0, isbg ? 0.f : m1,
                                  isbg ? 0.f : m2,
                                  cnt > 0.f ? cf / (3.f * cnt) : 0.f);
    W_g[b * 65 + i] = 300.f * dw[0] * sc;
    scale_sh[i] = sc;
    zf[i] = make_float4(isbg ? 0.f : m0, isbg ? 0.f : m1, isbg ? 0.f : m2, cf);
  }
  if (i == KINST) {
    A_g[b * 65 + KINST] = make_float4(0.f, 0.f, 0.f, 1.f);
    Z_g[b * 65 + KINST] = make_float4(0.f, 0.f, 0.f, 0.f);
    W_g[b * 65 + KINST] = 0.f;
  }
  __syncthreads();
  if (i == 0) flagp[b] = nu_sh;
  if (nu_sh) {
    float* ct = cw_g + (size_t)b * KINST * 65;
    for (int t2 = i; t2 < KINST * 65; t2 += blockDim.x) {
      int kk = t2 / 65, j = t2 - kk * 65;
      float v = 0.f;
      if (j < KINST && j != kk) v = 300.f * dw[kk * KINST + j] * scale_sh[kk];
      ct[t2] = v;
    }
  }
  // K^2 pairwise mean repulsion (same order as the old k_final loop)
  float psum = 0.f, pcnt = 0.f, cfs = 0.f;
  for (int idx = i; idx < KINST * KINST; idx += blockDim.x) {
    int j = idx >> 6, k = idx & 63;
    if (j < k) {
      float4 a = zf[j], c4 = zf[k];
      float m = a.w * c4.w;
      float d0 = a.x - c4.x, d1 = a.y - c4.y, d2 = a.z - c4.z;
      float sqd = d0 * d0 + d1 * d1 + d2 * d2;
      psum += dw[j * KINST + k] * 300.f / (sqd + 1.f) * m;
      pcnt += m;
    }
  }
  if (i < KINST) cfs = zf[i].w;
  for (int o = 32; o > 0; o >>= 1) {
    psum += __shfl_down(psum, o, 64);
    pcnt += __shfl_down(pcnt, o, 64);
    cfs += __shfl_down(cfs, o, 64);
  }
  int wid = i >> 6;
  if ((i & 63) == 0) { rA[wid] = psum; rB[wid] = pcnt; rC[wid] = cfs; }
  __syncthreads();
  if (i == 0) {
    float ps = 0.f, pc = 0.f, cs = 0.f;
    for (int x = 0; x < 4; ++x) { ps += rA[x]; pc += rB[x]; cs += rC[x]; }
    float mean_sep = pc > 0.f ? ps / fmaxf(pc, 1.f) : 0.f;
    msep_g[b] = make_float2(mean_sep, fmaxf(cs, 1.f));
  }
}

// ---------------------------------------------------------------------------
// Pass 3 (hot, identical to R14): pixel-per-lane, 4 px/thread; packed-f32
// inner loop; LDS uniform-broadcast tables.
// ---------------------------------------------------------------------------
template <bool USE_CACHE>
__global__ __launch_bounds__(256) void k_pix(const float* __restrict__ pred,
                                             const float* __restrict__ targ,
                                             const unsigned char* __restrict__ k0c,
                                             const int* __restrict__ pal,
                                             const float4* __restrict__ A_g,
                                             const float* __restrict__ W_g,
                                             const float4* __restrict__ Z_g,
                                             const float* __restrict__ cw_g,
                                             const int* __restrict__ flagp,
                                             float* __restrict__ res_part,
                                             int HW, int B) {
  int b = blockIdx.y;
  __shared__ float4 A_s[KINST + 1];
  __shared__ float4 Z_s[KINST + 1];
  __shared__ float W_s[KINST + 1];
  __shared__ float cwN[KINST][KINST + 1];
  __shared__ int pal_s[KINST];
  __shared__ int nonuni_s;
  __shared__ float rA[4], rB[4];
  int t = threadIdx.x;
  if (t < KINST + 1) {
    A_s[t] = A_g[b * 65 + t];
    Z_s[t] = Z_g[b * 65 + t];
    W_s[t] = W_g[b * 65 + t];
  }
  if (!USE_CACHE && t < KINST) pal_s[t] = pal[t];
  if (t == 0) {
    int f = 0;
    for (int bb = 0; bb < B; ++bb) f |= flagp[bb];
    nonuni_s = f;
  }
  __syncthreads();
  bool nonuni = nonuni_s != 0;
  if (nonuni) {
    const float* cwb = cw_g + (size_t)b * KINST * 65;
    for (int i = t; i < KINST * 65; i += blockDim.x) (&cwN[0][0])[i] = cwb[i];
    __syncthreads();
  }
  const float* pb = pred + (size_t)b * 3 * HW;
  const float* tb = targ + (size_t)b * 3 * HW;
  const float4* pb4 = (const float4*)pb;
  const float4* tb4 = (const float4*)tb;
  int nq = HW >> 2;
  const uchar4* kb4 = USE_CACHE ? (const uchar4*)(k0c + (size_t)b * HW) : nullptr;
  float intra_l = 0.f, inter_l = 0.f;
  for (int q = blockIdx.x * blockDim.x + t; q < nq;
       q += gridDim.x * blockDim.x) {
    float4 P0 = pb4[q], P1 = pb4[q + nq], P2 = pb4[q + 2 * nq];
    int ka, kc, kd, ke;
    if (USE_CACHE) {
      uchar4 kk = kb4[q];
      ka = kk.x; kc = kk.y; kd = kk.z; ke = kk.w;
    } else {
      float4 T0 = tb4[q], T1 = tb4[q + nq], T2 = tb4[q + 2 * nq];
      ka = decode_k0(T0.x, T1.x, T2.x, pal_s);
      kc = decode_k0(T0.y, T1.y, T2.y, pal_s);
      kd = decode_k0(T0.z, T1.z, T2.z, pal_s);
      ke = decode_k0(T0.w, T1.w, T2.w, pal_s);
    }
    float ppa = fmaf(P0.x, P0.x, fmaf(P1.x, P1.x, P2.x * P2.x));
    float ppb = fmaf(P0.y, P0.y, fmaf(P1.y, P1.y, P2.y * P2.y));
    float ppc = fmaf(P0.z, P0.z, fmaf(P1.z, P1.z, P2.z * P2.z));
    float ppd = fmaf(P0.w, P0.w, fmaf(P1.w, P1.w, P2.w * P2.w));
    float aa = 0.f, ab = 0.f, ac = 0.f, ad = 0.f;
    if (!nonuni) {
      v2f pp01 = {ppa, ppb}, pp23 = {ppc, ppd};
      v2f P0a = {P0.x, P0.y}, P0b = {P0.z, P0.w};
      v2f P1a = {P1.x, P1.y}, P1b = {P1.z, P1.w};
      v2f P2a = {P2.x, P2.y}, P2b = {P2.z, P2.w};
      v2f acc01 = {0.f, 0.f}, acc23 = {0.f, 0.f};
      #pragma unroll 8
      for (int k = 0; k < KINST; ++k) {
        float4 a = A_s[k];          // uniform addr -> broadcast b128
        float wv = W_s[k];          // uniform addr -> broadcast b32
        v2f ax = {a.x, a.x}, ay = {a.y, a.y}, az = {a.z, a.z}, aw = {a.w, a.w};
        v2f wv2 = {wv, wv};
        v2f t01 = __builtin_elementwise_fma(P0a, ax, aw);
        t01 = __builtin_elementwise_fma(P1a, ay, t01);
        t01 = __builtin_elementwise_fma(P2a, az, t01);
        v2f arg01 = pp01 + t01;
        v2f t23 = __builtin_elementwise_fma(P0b, ax, aw);
        t23 = __builtin_elementwise_fma(P1b, ay, t23);
        t23 = __builtin_elementwise_fma(P2b, az, t23);
        v2f arg23 = pp23 + t23;
        v2f r01 = {__builtin_amdgcn_rcpf(arg01.x), __builtin_amdgcn_rcpf(arg01.y)};
        v2f r23 = {__builtin_amdgcn_rcpf(arg23.x), __builtin_amdgcn_rcpf(arg23.y)};
        acc01 = __builtin_elementwise_fma(r01, wv2, acc01);
        acc23 = __builtin_elementwise_fma(r23, wv2, acc23);
      }
      aa = acc01.x; ab = acc01.y; ac = acc23.x; ad = acc23.y;
      // diagonal (k==k0) subtract + invalid-pixel mask (LDS gathers)
      {
        float4 a = A_s[ka]; float wv = W_s[ka];
        float r = __builtin_amdgcn_rcpf(
            ppa + fmaf(P0.x, a.x, fmaf(P1.x, a.y, fmaf(P2.x, a.z, a.w))));
        aa = (ka < KINST) ? aa - wv * r : 0.f;
      }
      {
        float4 a = A_s[kc]; float wv = W_s[kc];
        float r = __builtin_amdgcn_rcpf(
            ppb + fmaf(P0.y, a.x, fmaf(P1.y, a.y, fmaf(P2.y, a.z, a.w))));
        ab = (kc < KINST) ? ab - wv * r : 0.f;
      }
      {
        float4 a = A_s[kd]; float wv = W_s[kd];
        float r = __builtin_amdgcn_rcpf(
            ppc + fmaf(P0.z, a.x, fmaf(P1.z, a.y, fmaf(P2.z, a.z, a.w))));
        ac = (kd < KINST) ? ac - wv * r : 0.f;
      }
      {
        float4 a = A_s[ke]; float wv = W_s[ke];
        float r = __builtin_amdgcn_rcpf(
            ppd + fmaf(P0.w, a.x, fmaf(P1.w, a.y, fmaf(P2.w, a.z, a.w))));
        ad = (ke < KINST) ? ad - wv * r : 0.f;
      }
    } else {
      #pragma unroll 4
      for (int k = 0; k < KINST; ++k) {
        float4 a = A_s[k];
        float ra = __builtin_amdgcn_rcpf(
            ppa + fmaf(P0.x, a.x, fmaf(P1.x, a.y, fmaf(P2.x, a.z, a.w))));
        float rb = __builtin_amdgcn_rcpf(
            ppb + fmaf(P0.y, a.x, fmaf(P1.y, a.y, fmaf(P2.y, a.z, a.w))));
        float rc = __builtin_amdgcn_rcpf(
            ppc + fmaf(P0.z, a.x, fmaf(P1.z, a.y, fmaf(P2.z, a.z, a.w))));
        float rd = __builtin_amdgcn_rcpf(
            ppd + fmaf(P0.w, a.x, fmaf(P1.w, a.y, fmaf(P2.w, a.z, a.w))));
        aa = fmaf(ra, cwN[k][ka], aa); ab = fmaf(rb, cwN[k][kc], ab);
        ac = fmaf(rc, cwN[k][kd], ac); ad = fmaf(rd, cwN[k][ke], ad);
      }
    }
    inter_l += (aa + ab) + (ac + ad);
    // intra: huber toward own bg-zeroed mean; f_intra folds cf/(3*cnt)
    {
      float4 z = Z_s[ka];
      float q0 = fabsf(P0.x - z.x), q1 = fabsf(P1.x - z.y), q2 = fabsf(P2.x - z.z);
      float hp = (q0 < 1.f ? 0.5f * q0 * q0 : q0 - 0.5f) +
                 (q1 < 1.f ? 0.5f * q1 * q1 : q1 - 0.5f) +
                 (q2 < 1.f ? 0.5f * q2 * q2 : q2 - 0.5f);
      intra_l = fmaf(hp, z.w, intra_l);
    }
    {
      float4 z = Z_s[kc];
      float q0 = fabsf(P0.y - z.x), q1 = fabsf(P1.y - z.y), q2 = fabsf(P2.y - z.z);
      float hp = (q0 < 1.f ? 0.5f * q0 * q0 : q0 - 0.5f) +
                 (q1 < 1.f ? 0.5f * q1 * q1 : q1 - 0.5f) +
                 (q2 < 1.f ? 0.5f * q2 * q2 : q2 - 0.5f);
      intra_l = fmaf(hp, z.w, intra_l);
    }
    {
      float4 z = Z_s[kd];
      float q0 = fabsf(P0.z - z.x), q1 = fabsf(P1.z - z.y), q2 = fabsf(P2.z - z.z);
      float hp = (q0 < 1.f ? 0.5f * q0 * q0 : q0 - 0.5f) +
                 (q1 < 1.f ? 0.5f * q1 * q1 : q1 - 0.5f) +
                 (q2 < 1.f ? 0.5f * q2 * q2 : q2 - 0.5f);
      intra_l = fmaf(hp, z.w, intra_l);
    }
    {
      float4 z = Z_s[ke];
      float q0 = fabsf(P0.w - z.x), q1 = fabsf(P1.w - z.y), q2 = fabsf(P2.w - z.z);
      float hp = (q0 < 1.f ? 0.5f * q0 * q0 : q0 - 0.5f) +
                 (q1 < 1.f ? 0.5f * q1 * q1 : q1 - 0.5f) +
                 (q2 < 1.f ? 0.5f * q2 * q2 : q2 - 0.5f);
      intra_l = fmaf(hp, z.w, intra_l);
    }
  }
  // scalar tail pixels (HW % 4 != 0 only)
  for (int i = (nq << 2) + blockIdx.x * blockDim.x + t; i < HW;
       i += gridDim.x * blockDim.x) {
    float p0 = pb[i], p1 = pb[i + HW], p2 = pb[i + 2 * HW];
    int k0 = USE_CACHE ? (int)k0c[(size_t)b * HW + i]
                       : decode_k0(tb[i], tb[i + HW], tb[i + 2 * HW], pal_s);
    float pp = fmaf(p0, p0, fmaf(p1, p1, p2 * p2));
    float acc = 0.f;
    for (int k = 0; k < KINST; ++k) {
      float4 a = A_s[k];
      float r = __builtin_amdgcn_rcpf(
          pp + fmaf(p0, a.x, fmaf(p1, a.y, fmaf(p2, a.z, a.w))));
      float c = nonuni ? cwN[k][k0]
                       : ((k == k0 || k0 >= KINST) ? 0.f : W_s[k]);
      acc = fmaf(r, c, acc);
    }
    inter_l += acc;
    float4 z = Z_s[k0];
    float q0 = fabsf(p0 - z.x), q1 = fabsf(p1 - z.y), q2 = fabsf(p2 - z.z);
    float hp = (q0 < 1.f ? 0.5f * q0 * q0 : q0 - 0.5f) +
               (q1 < 1.f ? 0.5f * q1 * q1 : q1 - 0.5f) +
               (q2 < 1.f ? 0.5f * q2 * q2 : q2 - 0.5f);
    intra_l = fmaf(hp, z.w, intra_l);
  }
  for (int o = 32; o > 0; o >>= 1) {
    intra_l += __shfl_down(intra_l, o, 64);
    inter_l += __shfl_down(inter_l, o, 64);
  }
  int wid = t >> 6;
  if ((t & 63) == 0) { rA[wid] = intra_l; rB[wid] = inter_l; }
  __syncthreads();
  if (t == 0) {
    float a = 0.f, c = 0.f;
    for (int i = 0; i < 4; ++i) { a += rA[i]; c += rB[i]; }
    float* rp = res_part + ((size_t)b * gridDim.x + blockIdx.x) * 2;
    rp[0] = a; rp[1] = c;  // plain store, no atomics
  }
}

// ---------------------------------------------------------------------------
// Pass 4 (grid=B, light): reduce res_part + combine with msep; atomicAdd.
// ---------------------------------------------------------------------------
__global__ __launch_bounds__(256) void k_final(const float2* __restrict__ msep_g,
                                               const float* __restrict__ res_part,
                                               int ngx,
                                               float* __restrict__ out, int B) {
  int b = blockIdx.x;
  int t = threadIdx.x;
  __shared__ float rD[4], rE[4];
  float ra = 0.f, rc = 0.f;
  for (int bx = t; bx < ngx; bx += blockDim.x) {
    const float* rp = res_part + ((size_t)b * ngx + bx) * 2;
    ra += rp[0]; rc += rp[1];
  }
  for (int o = 32; o > 0; o >>= 1) {
    ra += __shfl_down(ra, o, 64);
    rc += __shfl_down(rc, o, 64);
  }
  int wid = t >> 6;
  if ((t & 63) == 0) { rD[wid] = ra; rE[wid] = rc; }
  __syncthreads();
  if (t == 0) {
    float sa = 0.f, sc2 = 0.f;
    for (int i = 0; i < 4; ++i) { sa += rD[i]; sc2 += rE[i]; }
    float2 ms = msep_g[b];
    atomicAdd(out, ((sa + sc2 + ms.x) / ms.y) / (float)B);
  }
}

extern "C" void kernel_launch(void* const* d_in, const int* in_sizes, int n_in,
                              void* d_out, int out_size, void* d_ws, size_t ws_size,
                              hipStream_t stream) {
  const float* pred = (const float*)d_in[0];
  const float* targ = (const float*)d_in[1];
  const unsigned char* nb = (const unsigned char*)d_in[2];
  const float* dw = (const float*)d_in[3];
  const int* pal = (const int*)d_in[4];
  int B = in_sizes[2];                 // 4
  int ndw = in_sizes[3];               // K*K = 4096
  int HW = in_sizes[0] / (3 * B);      // 262144  (kernels assume K==64)
  const int GX = 256;                  // k_pix blocks per b

  // ws layout (floats): partialS[B*nbs*256] | res_part[B*GX*2] | flagp[B]
  //   | msep[B*2] | A_g | W_g | Z_g | cw_g ; then bytes: k0c[B*HW]
  auto floats_needed = [&](int nbs) -> size_t {
    return (size_t)B * nbs * 256 + (size_t)B * GX * 2 + B + (size_t)B * 2 +
           (size_t)B * 65 * 4 + (size_t)B * 65 + (size_t)B * 65 * 4 +
           (size_t)B * KINST * 65;
  };
  int nbs = 64;
  bool use_cache = true;
  if (ws_size < floats_needed(64) * 4 + (size_t)B * HW) {
    if (ws_size >= floats_needed(32) * 4 + (size_t)B * HW) nbs = 32;
    else { nbs = 32; use_cache = false; }
  }
  float* partialS = (float*)d_ws;
  float* res_part = partialS + (size_t)B * nbs * 256;
  int* flagp = (int*)(res_part + (size_t)B * GX * 2);
  float2* msep_g = (float2*)(flagp + B);
  float4* A_g = (float4*)(msep_g + B);
  float* W_g = (float*)(A_g + (size_t)B * 65);
  float4* Z_g = (float4*)(W_g + (size_t)B * 65);
  float* cw_g = (float*)(Z_g + (size_t)B * 65);
  unsigned char* k0c = use_cache ? (unsigned char*)(cw_g + (size_t)B * KINST * 65)
                                 : nullptr;

  k_stats<<<dim3(nbs, B), 256, 0, stream>>>(pred, targ, pal, partialS, k0c,
                                            (float*)d_out, HW);
  k_reduce<<<B, 256, 0, stream>>>(partialS, dw, pal, nb, ndw, nbs, A_g, W_g,
                                  Z_g, cw_g, flagp, msep_g, B, HW);
  if (use_cache)
    k_pix<true><<<dim3(GX, B), 256, 0, stream>>>(pred, targ, k0c, pal, A_g, W_g,
                                                 Z_g, cw_g, flagp, res_part, HW, B);
  else
    k_pix<false><<<dim3(GX, B), 256, 0, stream>>>(pred, targ, k0c, pal, A_g, W_g,
                                                  Z_g, cw_g, flagp, res_part, HW, B);
  k_final<<<B, 256, 0, stream>>>(msep_g, res_part, GX, (float*)d_out, B);
}